// Round 19
// baseline (93.247 us; speedup 1.0000x reference)
//
#include <hip/hip_runtime.h>

// GCN 2-layer, 5 dispatches:
//   zero: clear bfill (16KB) only
//   binA: chunk-wise LDS counting sort of edges by dst-bucket (512 nodes),
//         register-stashed edges, 64B-aligned reservations into FIXED
//         per-bucket regions (b*CAP). 8-lane-group burst copy.
//   binB: TWO blocks per bucket (one per 256-node half): stream bucket
//         region, filter own half, hist -> scan -> cnt/dis/rstart/xd,
//         scatter into 48KB LDS srt, burst copy -> esrc region (2b+hf)*HCAP.
//         (halves LDS -> 3 blocks/CU, doubles parallelism vs 96KB/1 per CU)
//   layer1: per-node 8-lane gather-aggregate of xd rows (32B, L2-resident),
//         16 independent gathers in flight; then in-register MLP -> g2
//   out2: per-node 4-lane gather-aggregate of g2 -> out, 8 gathers in flight
// norm trick: g = dis*(h@W); out[v] = dis[v]*(sum_{u->v} g[u] + g[v]) + b.

static constexpr int F0 = 16;
static constexpr int F1 = 32;
static constexpr int F2 = 2;
static constexpr int BSH  = 9;      // bucket = dst>>9 (512 nodes)
static constexpr int BMSK = 511;
static constexpr int MAXNB = 256;   // max coarse buckets (scan width)
static constexpr int NBMAX = 196;   // actual bucket count for N=100000
static constexpr int BPAD  = 16;    // cursor padded to own 64B line
static constexpr int EPB   = 8192;  // edges per binA chunk (= 16 per thread)
static constexpr int CAP   = 24576; // slots per bucket region
static constexpr int HCAP  = CAP / 2;  // 12288 slots per half-bucket esrc region
static constexpr int SORTCAP = EPB + NBMAX * 16;   // 11328 (~45KB)
static constexpr unsigned SENT = 0xFFFFFFFFu;

__device__ inline unsigned roundup16(unsigned h) { return (h + 15u) & ~15u; }

__device__ inline unsigned f2bf(float f) {
    unsigned u = __float_as_uint(f);
    return (u + 0x7fffu + ((u >> 16) & 1u)) >> 16;   // RNE
}
__device__ inline float bf2f(unsigned b) {
    return __uint_as_float(b << 16);
}

// grid-stride zero
__global__ void k_zero(unsigned* __restrict__ p, int n) {
    int i = blockIdx.x * blockDim.x + threadIdx.x;
    if (i < n) p[i] = 0u;
}

// LDS counting sort of a chunk (edges stashed in registers; one global read),
// then per-bucket 8-lane-group burst copy to global.
__global__ __launch_bounds__(512) void k_binA(const int* __restrict__ src,
                                              const int* __restrict__ dst,
                                              unsigned* __restrict__ bfill,
                                              unsigned* __restrict__ pairs,
                                              int E, int nb) {
    __shared__ unsigned h[MAXNB];
    __shared__ unsigned lbase[MAXNB];
    __shared__ unsigned bs_[MAXNB];
    __shared__ unsigned cur[MAXNB];
    __shared__ unsigned wsum[8];
    __shared__ unsigned wbase[8];
    __shared__ __attribute__((aligned(16))) unsigned sorted[SORTCAP];
    int tid = threadIdx.x;
    for (int b = tid; b < MAXNB; b += 512) { h[b] = 0; cur[b] = 0; }
    if (tid < 8) wsum[tid] = 0;
    __syncthreads();
    int e0 = blockIdx.x * EPB;
    int cn = min(EPB, E - e0);
    unsigned key[16];
    unsigned bkt[16];
#pragma unroll
    for (int j = 0; j < 16; ++j) {
        int idx = j * 512 + tid;
        if (idx < cn) {
            unsigned d = (unsigned)dst[e0 + idx];
            unsigned s = (unsigned)src[e0 + idx];
            unsigned b = d >> BSH;
            key[j] = (s << BSH) | (d & BMSK);
            bkt[j] = b;
            atomicAdd(&h[b], 1u);
        }
    }
    __syncthreads();
    // exclusive scan of roundup16(h) over 256 entries: wave shfl scan
    unsigned pv = 0, px = 0;
    if (tid < MAXNB) {
        pv = roundup16(h[tid]);
        px = pv;
#pragma unroll
        for (int off = 1; off < 64; off <<= 1) {
            unsigned t = __shfl_up(px, off, 64);
            if ((tid & 63) >= off) px += t;
        }
        if ((tid & 63) == 63) wsum[tid >> 6] = px;
    }
    __syncthreads();
    if (tid < 8) {
        unsigned acc = 0;
        for (int k = 0; k < tid; ++k) acc += wsum[k];
        wbase[tid] = acc;
    }
    __syncthreads();
    if (tid < MAXNB) {
        unsigned ex = px - pv + wbase[tid >> 6];
        lbase[tid] = ex;
        if (tid < nb && h[tid])
            bs_[tid] = (unsigned)(tid * CAP) + atomicAdd(&bfill[tid * BPAD], roundup16(h[tid]));
    }
    __syncthreads();
    // scatter from registers into LDS (bucket-sorted)
#pragma unroll
    for (int j = 0; j < 16; ++j) {
        int idx = j * 512 + tid;
        if (idx < cn) {
            unsigned b = bkt[j];
            unsigned pos = lbase[b] + atomicAdd(&cur[b], 1u);
            sorted[pos] = key[j];
        }
    }
    // sentinel-fill ONLY the pad slots
    for (int b = tid; b < nb; b += 512) {
        unsigned hb = h[b];
        if (!hb) continue;
        unsigned k0 = lbase[b] + hb;
        unsigned k1 = lbase[b] + roundup16(hb);
        for (unsigned k = k0; k < k1; ++k) sorted[k] = SENT;
    }
    __syncthreads();
    // burst copy: 8-lane group per bucket (64 groups), uint4 contiguous stores
    int grp = tid >> 3;
    int ln8 = tid & 7;
    for (int b = grp; b < nb; b += 64) {
        unsigned np = roundup16(h[b]) >> 2;   // uint4 count
        if (!np) continue;
        const uint4* sp = reinterpret_cast<const uint4*>(&sorted[lbase[b]]);
        uint4* gp = reinterpret_cast<uint4*>(&pairs[bs_[b]]);
        for (unsigned k = ln8; k < np; k += 8) gp[k] = sp[k];
    }
}

// per-HALF-bucket: stream bucket region, filter own half (256 nodes),
// hist -> wave scan -> cnt/dis/rstart/xd, scatter into LDS srt (48KB),
// coalesced uint4 burst -> esrc region (2b+hf)*HCAP.
__global__ __launch_bounds__(512) void k_binB(const unsigned* __restrict__ pairs,
                                              const unsigned* __restrict__ bfill,
                                              const float* __restrict__ x,
                                              int* __restrict__ cnt, float* __restrict__ dis,
                                              int* __restrict__ rstart, int* __restrict__ esrc,
                                              unsigned* __restrict__ xd, int N) {
    __shared__ unsigned h[256];
    __shared__ unsigned cur[256];    // scatter cursor (starts at exclusive scan)
    __shared__ unsigned wsum[4];
    __shared__ unsigned wbase[4];
    __shared__ unsigned tot_s;
    __shared__ __attribute__((aligned(16))) unsigned srt[HCAP];  // 48KB
    int tid = threadIdx.x;
    int b = blockIdx.x >> 1;
    unsigned hf = blockIdx.x & 1;
    if (tid < 256) { h[tid] = 0; }
    __syncthreads();
    int r0 = b * CAP;
    int n4 = (int)bfill[b * BPAD] >> 2;
    const uint4* p4 = reinterpret_cast<const uint4*>(pairs + r0);
    for (int i = tid; i < n4; i += 512) {
        uint4 p = p4[i];
        if (p.x != SENT && ((p.x >> 8) & 1u) == hf) atomicAdd(&h[p.x & 255u], 1u);
        if (p.y != SENT && ((p.y >> 8) & 1u) == hf) atomicAdd(&h[p.y & 255u], 1u);
        if (p.z != SENT && ((p.z >> 8) & 1u) == hf) atomicAdd(&h[p.z & 255u], 1u);
        if (p.w != SENT && ((p.w >> 8) & 1u) == hf) atomicAdd(&h[p.w & 255u], 1u);
    }
    __syncthreads();
    // exclusive scan over 256 counts (first 256 threads): wave shfl scan
    int er0 = (int)(blockIdx.x * HCAP);
    if (tid < 256) {
        unsigned v = h[tid];
        unsigned x2 = v;
#pragma unroll
        for (int off = 1; off < 64; off <<= 1) {
            unsigned t = __shfl_up(x2, off, 64);
            if ((tid & 63) >= off) x2 += t;
        }
        if ((tid & 63) == 63) wsum[tid >> 6] = x2;
        __syncthreads();
        if (tid < 4) {
            unsigned acc = 0;
            for (int k = 0; k < tid; ++k) acc += wsum[k];
            wbase[tid] = acc;
        }
        __syncthreads();
        unsigned ex = x2 - v + wbase[tid >> 6];
        cur[tid] = ex;
        if (tid == 255) tot_s = ex + v;
        int node = (b << BSH) + ((int)hf << 8) + tid;
        if (node < N) {
            float d = rsqrtf((float)(v + 1u));
            cnt[node] = (int)v;
            dis[node] = d;
            rstart[node] = er0 + (int)ex;
            const float4* xp = reinterpret_cast<const float4*>(x + (size_t)node * F0);
            unsigned pk[8];
#pragma unroll
            for (int q = 0; q < 4; ++q) {
                float4 vv = xp[q];
                pk[2 * q + 0] = f2bf(d * vv.x) | (f2bf(d * vv.y) << 16);
                pk[2 * q + 1] = f2bf(d * vv.z) | (f2bf(d * vv.w) << 16);
            }
            uint4* o = reinterpret_cast<uint4*>(xd + (size_t)node * 8);
            o[0] = make_uint4(pk[0], pk[1], pk[2], pk[3]);
            o[1] = make_uint4(pk[4], pk[5], pk[6], pk[7]);
        }
    } else {
        __syncthreads();
        __syncthreads();
    }
    __syncthreads();
    // pass2: re-read pairs (L2-warm), scatter own half into LDS srt
    for (int i = tid; i < n4; i += 512) {
        uint4 p = p4[i];
        if (p.x != SENT && ((p.x >> 8) & 1u) == hf) { unsigned o_ = atomicAdd(&cur[p.x & 255u], 1u); srt[o_] = p.x >> BSH; }
        if (p.y != SENT && ((p.y >> 8) & 1u) == hf) { unsigned o_ = atomicAdd(&cur[p.y & 255u], 1u); srt[o_] = p.y >> BSH; }
        if (p.z != SENT && ((p.z >> 8) & 1u) == hf) { unsigned o_ = atomicAdd(&cur[p.z & 255u], 1u); srt[o_] = p.z >> BSH; }
        if (p.w != SENT && ((p.w >> 8) & 1u) == hf) { unsigned o_ = atomicAdd(&cur[p.w & 255u], 1u); srt[o_] = p.w >> BSH; }
    }
    __syncthreads();
    // coalesced burst copy srt -> esrc (uint4; tail reads harmless garbage)
    unsigned tot4 = (tot_s + 3u) >> 2;
    const uint4* s4 = reinterpret_cast<const uint4*>(srt);
    uint4* g4 = reinterpret_cast<uint4*>(esrc + er0);
    for (unsigned k = tid; k < tot4; k += 512) g4[k] = s4[k];
}

// fused layer1: 8 lanes/node gather-aggregate xd (1 u32/lane = 32B/row),
// 16-edge chunks (16 independent gathers in flight), then in-register MLP.
__global__ void k_layer1(const unsigned* __restrict__ xd, const int* __restrict__ cnt,
                         const int* __restrict__ rstart, const int* __restrict__ esrc,
                         const float* __restrict__ dis, const float* __restrict__ b1,
                         const float* __restrict__ W1, const float* __restrict__ W2,
                         float* __restrict__ g2, int N) {
    __shared__ float w1[F0 * F1];
    __shared__ float w2[F1 * F2];
    __shared__ float bb[F1];
    __shared__ float ymat[32][17];   // 32 nodes/block, +1 pad
    for (int j = threadIdx.x; j < F0 * F1; j += blockDim.x) w1[j] = W1[j];
    for (int j = threadIdx.x; j < F1 * F2; j += blockDim.x) w2[j] = W2[j];
    for (int j = threadIdx.x; j < F1; j += blockDim.x) bb[j] = b1[j];
    __syncthreads();
    int t = blockIdx.x * blockDim.x + threadIdx.x;
    int v = t >> 3;
    int q = t & 7;
    if (v >= N) return;
    const unsigned* base = xd + q;             // row stride 8 u32
    unsigned sw = base[(size_t)v * 8];         // self loop xd[v]
    float a0 = bf2f(sw & 0xffffu);
    float a1 = bf2f(sw >> 16);
    int beg = rstart[v];
    int n = cnt[v];
    int j = 0;
    for (; j + 16 <= n; j += 16) {             // 16 edges: 2 idx/lane
        int ia = esrc[beg + j + 2 * q];
        int ib = esrc[beg + j + 2 * q + 1];
#pragma unroll
        for (int u = 0; u < 8; ++u) {
            int s0 = __shfl(ia, u, 8);
            int s1 = __shfl(ib, u, 8);
            unsigned a = base[(size_t)s0 * 8];
            unsigned c = base[(size_t)s1 * 8];
            a0 += bf2f(a & 0xffffu) + bf2f(c & 0xffffu);
            a1 += bf2f(a >> 16) + bf2f(c >> 16);
        }
    }
    if (j + 8 <= n) {                          // one 8-edge chunk
        int idx = esrc[beg + j + q];
#pragma unroll
        for (int u = 0; u < 8; ++u) {
            int s = __shfl(idx, u, 8);
            unsigned a = base[(size_t)s * 8];
            a0 += bf2f(a & 0xffffu);
            a1 += bf2f(a >> 16);
        }
        j += 8;
    }
    for (; j < n; ++j) {                       // tail: uniform load
        int s = esrc[beg + j];
        unsigned a = base[(size_t)s * 8];
        a0 += bf2f(a & 0xffffu);
        a1 += bf2f(a >> 16);
    }
    // exchange y within the 8-lane group (wave-local LDS, lockstep)
    int ln = threadIdx.x >> 3;
    ymat[ln][2 * q + 0] = a0;
    ymat[ln][2 * q + 1] = a1;
    float y[F0];
#pragma unroll
    for (int k = 0; k < F0; ++k) y[k] = ymat[ln][k];
    float d = dis[v];
    float p0 = 0.0f, p1 = 0.0f;
#pragma unroll
    for (int u = 0; u < 4; ++u) {
        int jf = q * 4 + u;                    // 32 features across 8 lanes x 4
        float s = 0.0f;
#pragma unroll
        for (int k = 0; k < F0; ++k) s = fmaf(y[k], w1[k * F1 + jf], s);
        float r = fmaxf(fmaf(d, s, bb[jf]), 0.0f);
        p0 = fmaf(r, w2[jf * F2 + 0], p0);
        p1 = fmaf(r, w2[jf * F2 + 1], p1);
    }
#pragma unroll
    for (int off = 1; off < 8; off <<= 1) {
        p0 += __shfl_xor(p0, off);
        p1 += __shfl_xor(p1, off);
    }
    if (q == 0) {
        g2[(size_t)v * F2 + 0] = d * p0;
        g2[(size_t)v * F2 + 1] = d * p1;
    }
}

// fused layer2 aggregate + output: 4 lanes per node, 8 gathers in flight
__global__ void k_out2(const float* __restrict__ g2, const int* __restrict__ cnt,
                       const int* __restrict__ rstart, const int* __restrict__ esrc,
                       const float* __restrict__ dis, const float* __restrict__ b2,
                       float* __restrict__ out, int N) {
    int t = blockIdx.x * blockDim.x + threadIdx.x;
    int v = t >> 2;
    int l = t & 3;
    if (v >= N) return;
    float o0 = 0.0f, o1 = 0.0f;
    int beg = rstart[v];
    int end = beg + cnt[v];
    int j = beg + l;
    for (; j + 28 < end; j += 32) {        // 8 independent gathers in flight
        int s0 = esrc[j];
        int s1 = esrc[j + 4];
        int s2 = esrc[j + 8];
        int s3 = esrc[j + 12];
        int s4 = esrc[j + 16];
        int s5 = esrc[j + 20];
        int s6 = esrc[j + 24];
        int s7 = esrc[j + 28];
        float2 a0 = *reinterpret_cast<const float2*>(g2 + (size_t)s0 * F2);
        float2 a1 = *reinterpret_cast<const float2*>(g2 + (size_t)s1 * F2);
        float2 a2 = *reinterpret_cast<const float2*>(g2 + (size_t)s2 * F2);
        float2 a3 = *reinterpret_cast<const float2*>(g2 + (size_t)s3 * F2);
        float2 a4 = *reinterpret_cast<const float2*>(g2 + (size_t)s4 * F2);
        float2 a5 = *reinterpret_cast<const float2*>(g2 + (size_t)s5 * F2);
        float2 a6 = *reinterpret_cast<const float2*>(g2 + (size_t)s6 * F2);
        float2 a7 = *reinterpret_cast<const float2*>(g2 + (size_t)s7 * F2);
        o0 += a0.x + a1.x + a2.x + a3.x + a4.x + a5.x + a6.x + a7.x;
        o1 += a0.y + a1.y + a2.y + a3.y + a4.y + a5.y + a6.y + a7.y;
    }
    for (; j + 12 < end; j += 16) {        // 4 in flight
        int s0 = esrc[j];
        int s1 = esrc[j + 4];
        int s2 = esrc[j + 8];
        int s3 = esrc[j + 12];
        float2 a0 = *reinterpret_cast<const float2*>(g2 + (size_t)s0 * F2);
        float2 a1 = *reinterpret_cast<const float2*>(g2 + (size_t)s1 * F2);
        float2 a2 = *reinterpret_cast<const float2*>(g2 + (size_t)s2 * F2);
        float2 a3 = *reinterpret_cast<const float2*>(g2 + (size_t)s3 * F2);
        o0 += a0.x + a1.x + a2.x + a3.x;
        o1 += a0.y + a1.y + a2.y + a3.y;
    }
    for (; j < end; j += 4) {
        int s = esrc[j];
        const float2 a = *reinterpret_cast<const float2*>(g2 + (size_t)s * F2);
        o0 += a.x; o1 += a.y;
    }
#pragma unroll
    for (int off = 1; off < 4; off <<= 1) {
        o0 += __shfl_xor(o0, off);
        o1 += __shfl_xor(o1, off);
    }
    if (l == 0) {
        float d = dis[v];
        const float2 self = *reinterpret_cast<const float2*>(g2 + (size_t)v * F2);
        out[(size_t)v * F2 + 0] = fmaf(d, o0 + self.x, b2[0]);
        out[(size_t)v * F2 + 1] = fmaf(d, o1 + self.y, b2[1]);
    }
}

extern "C" void kernel_launch(void* const* d_in, const int* in_sizes, int n_in,
                              void* d_out, int out_size, void* d_ws, size_t ws_size,
                              hipStream_t stream) {
    const float* x  = (const float*)d_in[0];
    const int* ei   = (const int*)d_in[1];
    const float* W1 = (const float*)d_in[2];
    const float* b1 = (const float*)d_in[3];
    const float* W2 = (const float*)d_in[4];
    const float* b2 = (const float*)d_in[5];
    float* out = (float*)d_out;

    const int N = in_sizes[0] / F0;          // 100000
    const int E = in_sizes[1] / 2;           // 3200000
    const int* src = ei;
    const int* dst = ei + E;
    const int nb = (N + BMSK) >> BSH;        // 196 buckets of 512 nodes
    const int nchunk = (E + EPB - 1) / EPB;  // 391 chunks

    // workspace layout (u32 units); pairs 16B-aligned
    unsigned* bfill = (unsigned*)d_ws;                    // MAXNB*BPAD (16KB)
    unsigned* pairs = bfill + MAXNB * BPAD;               // nb*CAP (~19.3MB)
    int* esrc       = (int*)(pairs + (size_t)nb * CAP);   // nb*CAP (~19.3MB)
    unsigned* xd    = (unsigned*)(esrc + (size_t)nb * CAP); // 8N (32B rows)
    float* dis      = (float*)(xd + (size_t)8 * N);       // N
    int* cnt        = (int*)(dis + N);                    // N
    int* rstart     = cnt + N;                            // N
    float* g2       = (float*)(rstart + N);               // 2N
    // total ~ 44 MB

    const int B = 256;
    const int nz = MAXNB * BPAD;
    k_zero<<<(nz + B - 1) / B, B, 0, stream>>>(bfill, nz);
    k_binA<<<nchunk, 512, 0, stream>>>(src, dst, bfill, pairs, E, nb);
    k_binB<<<nb * 2, 512, 0, stream>>>(pairs, bfill, x, cnt, dis, rstart, esrc, xd, N);
    k_layer1<<<(N * 8 + B - 1) / B, B, 0, stream>>>(xd, cnt, rstart, esrc, dis, b1, W1, W2, g2, N);
    k_out2<<<(N * 4 + B - 1) / B, B, 0, stream>>>(g2, cnt, rstart, esrc, dis, b2, out, N);
}

// Round 20
// 87.700 us; speedup vs baseline: 1.0632x; 1.0632x over previous
//
#include <hip/hip_runtime.h>

// GCN 2-layer, 5 dispatches:
//   zero: clear bfill (16KB) only
//   binA: chunk-wise LDS counting sort of edges by dst-bucket (512 nodes),
//         register-stashed edges, 64B-aligned reservations into FIXED
//         per-bucket regions (b*CAP). 8-lane-group burst copy.
//   binB: one block per bucket, 1024 threads (16 waves/CU; LDS caps at
//         1 block/CU so extra waves are free): uint4 hist pass -> wave scan
//         -> cnt/dis/rstart/xd, pass2 scatter into 96KB LDS srt, then
//         coalesced uint4 burst copy -> node-sorted esrc.
//         (round-19 half-bucket split REVERTED: it doubled region streaming)
//   layer1: per-node 8-lane gather-aggregate of xd rows (32B, L2-resident),
//         16 independent gathers in flight; then in-register MLP -> g2
//   out2: per-node 4-lane gather-aggregate of g2 -> out, 8 gathers in flight
// norm trick: g = dis*(h@W); out[v] = dis[v]*(sum_{u->v} g[u] + g[v]) + b.

static constexpr int F0 = 16;
static constexpr int F1 = 32;
static constexpr int F2 = 2;
static constexpr int BSH  = 9;      // bucket = dst>>9 (512 nodes)
static constexpr int BMSK = 511;
static constexpr int NPB  = 512;    // nodes per bucket
static constexpr int MAXNB = 256;   // max coarse buckets (scan width)
static constexpr int NBMAX = 196;   // actual bucket count for N=100000
static constexpr int BPAD  = 16;    // cursor padded to own 64B line
static constexpr int EPB   = 8192;  // edges per binA chunk (= 16 per thread)
static constexpr int CAP   = 24576; // slots per bucket region
static constexpr int SORTCAP = EPB + NBMAX * 16;   // 11328 (~45KB)
static constexpr unsigned SENT = 0xFFFFFFFFu;

__device__ inline unsigned roundup16(unsigned h) { return (h + 15u) & ~15u; }

__device__ inline unsigned f2bf(float f) {
    unsigned u = __float_as_uint(f);
    return (u + 0x7fffu + ((u >> 16) & 1u)) >> 16;   // RNE
}
__device__ inline float bf2f(unsigned b) {
    return __uint_as_float(b << 16);
}

// grid-stride zero
__global__ void k_zero(unsigned* __restrict__ p, int n) {
    int i = blockIdx.x * blockDim.x + threadIdx.x;
    if (i < n) p[i] = 0u;
}

// LDS counting sort of a chunk (edges stashed in registers; one global read),
// then per-bucket 8-lane-group burst copy to global.
__global__ __launch_bounds__(512) void k_binA(const int* __restrict__ src,
                                              const int* __restrict__ dst,
                                              unsigned* __restrict__ bfill,
                                              unsigned* __restrict__ pairs,
                                              int E, int nb) {
    __shared__ unsigned h[MAXNB];
    __shared__ unsigned lbase[MAXNB];
    __shared__ unsigned bs_[MAXNB];
    __shared__ unsigned cur[MAXNB];
    __shared__ unsigned wsum[8];
    __shared__ unsigned wbase[8];
    __shared__ __attribute__((aligned(16))) unsigned sorted[SORTCAP];
    int tid = threadIdx.x;
    for (int b = tid; b < MAXNB; b += 512) { h[b] = 0; cur[b] = 0; }
    if (tid < 8) wsum[tid] = 0;
    __syncthreads();
    int e0 = blockIdx.x * EPB;
    int cn = min(EPB, E - e0);
    unsigned key[16];
    unsigned bkt[16];
#pragma unroll
    for (int j = 0; j < 16; ++j) {
        int idx = j * 512 + tid;
        if (idx < cn) {
            unsigned d = (unsigned)dst[e0 + idx];
            unsigned s = (unsigned)src[e0 + idx];
            unsigned b = d >> BSH;
            key[j] = (s << BSH) | (d & BMSK);
            bkt[j] = b;
            atomicAdd(&h[b], 1u);
        }
    }
    __syncthreads();
    // exclusive scan of roundup16(h) over 256 entries: wave shfl scan
    unsigned pv = 0, px = 0;
    if (tid < MAXNB) {
        pv = roundup16(h[tid]);
        px = pv;
#pragma unroll
        for (int off = 1; off < 64; off <<= 1) {
            unsigned t = __shfl_up(px, off, 64);
            if ((tid & 63) >= off) px += t;
        }
        if ((tid & 63) == 63) wsum[tid >> 6] = px;
    }
    __syncthreads();
    if (tid < 8) {
        unsigned acc = 0;
        for (int k = 0; k < tid; ++k) acc += wsum[k];
        wbase[tid] = acc;
    }
    __syncthreads();
    if (tid < MAXNB) {
        unsigned ex = px - pv + wbase[tid >> 6];
        lbase[tid] = ex;
        if (tid < nb && h[tid])
            bs_[tid] = (unsigned)(tid * CAP) + atomicAdd(&bfill[tid * BPAD], roundup16(h[tid]));
    }
    __syncthreads();
    // scatter from registers into LDS (bucket-sorted)
#pragma unroll
    for (int j = 0; j < 16; ++j) {
        int idx = j * 512 + tid;
        if (idx < cn) {
            unsigned b = bkt[j];
            unsigned pos = lbase[b] + atomicAdd(&cur[b], 1u);
            sorted[pos] = key[j];
        }
    }
    // sentinel-fill ONLY the pad slots
    for (int b = tid; b < nb; b += 512) {
        unsigned hb = h[b];
        if (!hb) continue;
        unsigned k0 = lbase[b] + hb;
        unsigned k1 = lbase[b] + roundup16(hb);
        for (unsigned k = k0; k < k1; ++k) sorted[k] = SENT;
    }
    __syncthreads();
    // burst copy: 8-lane group per bucket (64 groups), uint4 contiguous stores
    int grp = tid >> 3;
    int ln8 = tid & 7;
    for (int b = grp; b < nb; b += 64) {
        unsigned np = roundup16(h[b]) >> 2;   // uint4 count
        if (!np) continue;
        const uint4* sp = reinterpret_cast<const uint4*>(&sorted[lbase[b]]);
        uint4* gp = reinterpret_cast<uint4*>(&pairs[bs_[b]]);
        for (unsigned k = ln8; k < np; k += 8) gp[k] = sp[k];
    }
}

// per-bucket (1024 threads): hist pass -> wave scan -> cnt/dis/rstart/xd;
// pass2 scatters into 96KB LDS srt, then coalesced uint4 burst -> esrc.
__global__ __launch_bounds__(1024) void k_binB(const unsigned* __restrict__ pairs,
                                               const unsigned* __restrict__ bfill,
                                               const float* __restrict__ x,
                                               int* __restrict__ cnt, float* __restrict__ dis,
                                               int* __restrict__ rstart, int* __restrict__ esrc,
                                               unsigned* __restrict__ xd, int N) {
    __shared__ unsigned h[NPB];
    __shared__ unsigned cur[NPB];    // scatter cursor (starts at exclusive scan)
    __shared__ unsigned wsum[8];
    __shared__ unsigned wbase[8];
    __shared__ unsigned tot_s;
    __shared__ __attribute__((aligned(16))) unsigned srt[CAP];   // 96KB node-sorted
    int tid = threadIdx.x, b = blockIdx.x;
    if (tid < NPB) h[tid] = 0;
    __syncthreads();
    int r0 = b * CAP;
    int n4 = (int)bfill[b * BPAD] >> 2;
    const uint4* p4 = reinterpret_cast<const uint4*>(pairs + r0);
    for (int i = tid; i < n4; i += 1024) {
        uint4 p = p4[i];
        if (p.x != SENT) atomicAdd(&h[p.x & BMSK], 1u);
        if (p.y != SENT) atomicAdd(&h[p.y & BMSK], 1u);
        if (p.z != SENT) atomicAdd(&h[p.z & BMSK], 1u);
        if (p.w != SENT) atomicAdd(&h[p.w & BMSK], 1u);
    }
    __syncthreads();
    // exclusive scan over 512 counts (first 512 threads): wave shfl scan
    unsigned v = 0, x2 = 0;
    if (tid < NPB) {
        v = h[tid];
        x2 = v;
#pragma unroll
        for (int off = 1; off < 64; off <<= 1) {
            unsigned t = __shfl_up(x2, off, 64);
            if ((tid & 63) >= off) x2 += t;
        }
        if ((tid & 63) == 63) wsum[tid >> 6] = x2;
    }
    __syncthreads();
    if (tid < 8) {
        unsigned acc = 0;
        for (int k = 0; k < tid; ++k) acc += wsum[k];
        wbase[tid] = acc;
    }
    __syncthreads();
    if (tid < NPB) {
        unsigned ex = x2 - v + wbase[tid >> 6];
        cur[tid] = ex;               // block-relative compact cursor
        if (tid == NPB - 1) tot_s = ex + v;
        int node = (b << BSH) + tid;
        if (node < N) {
            float d = rsqrtf((float)(v + 1u));
            cnt[node] = (int)v;
            dis[node] = d;
            rstart[node] = r0 + (int)ex;
            const float4* xp = reinterpret_cast<const float4*>(x + (size_t)node * F0);
            unsigned pk[8];
#pragma unroll
            for (int q = 0; q < 4; ++q) {
                float4 vv = xp[q];
                pk[2 * q + 0] = f2bf(d * vv.x) | (f2bf(d * vv.y) << 16);
                pk[2 * q + 1] = f2bf(d * vv.z) | (f2bf(d * vv.w) << 16);
            }
            uint4* o = reinterpret_cast<uint4*>(xd + (size_t)node * 8);
            o[0] = make_uint4(pk[0], pk[1], pk[2], pk[3]);
            o[1] = make_uint4(pk[4], pk[5], pk[6], pk[7]);
        }
    }
    __syncthreads();
    // pass2: re-read pairs (L2-warm), scatter into LDS srt (on-chip)
    for (int i = tid; i < n4; i += 1024) {
        uint4 p = p4[i];
        if (p.x != SENT) { unsigned o_ = atomicAdd(&cur[p.x & BMSK], 1u); srt[o_] = p.x >> BSH; }
        if (p.y != SENT) { unsigned o_ = atomicAdd(&cur[p.y & BMSK], 1u); srt[o_] = p.y >> BSH; }
        if (p.z != SENT) { unsigned o_ = atomicAdd(&cur[p.z & BMSK], 1u); srt[o_] = p.z >> BSH; }
        if (p.w != SENT) { unsigned o_ = atomicAdd(&cur[p.w & BMSK], 1u); srt[o_] = p.w >> BSH; }
    }
    __syncthreads();
    // coalesced burst copy srt -> esrc (uint4; tail reads harmless garbage)
    unsigned tot4 = (tot_s + 3u) >> 2;
    const uint4* s4 = reinterpret_cast<const uint4*>(srt);
    uint4* g4 = reinterpret_cast<uint4*>(esrc + r0);
    for (unsigned k = tid; k < tot4; k += 1024) g4[k] = s4[k];
}

// fused layer1: 8 lanes/node gather-aggregate xd (1 u32/lane = 32B/row),
// 16-edge chunks (16 independent gathers in flight), then in-register MLP.
__global__ void k_layer1(const unsigned* __restrict__ xd, const int* __restrict__ cnt,
                         const int* __restrict__ rstart, const int* __restrict__ esrc,
                         const float* __restrict__ dis, const float* __restrict__ b1,
                         const float* __restrict__ W1, const float* __restrict__ W2,
                         float* __restrict__ g2, int N) {
    __shared__ float w1[F0 * F1];
    __shared__ float w2[F1 * F2];
    __shared__ float bb[F1];
    __shared__ float ymat[32][17];   // 32 nodes/block, +1 pad
    for (int j = threadIdx.x; j < F0 * F1; j += blockDim.x) w1[j] = W1[j];
    for (int j = threadIdx.x; j < F1 * F2; j += blockDim.x) w2[j] = W2[j];
    for (int j = threadIdx.x; j < F1; j += blockDim.x) bb[j] = b1[j];
    __syncthreads();
    int t = blockIdx.x * blockDim.x + threadIdx.x;
    int v = t >> 3;
    int q = t & 7;
    if (v >= N) return;
    const unsigned* base = xd + q;             // row stride 8 u32
    unsigned sw = base[(size_t)v * 8];         // self loop xd[v]
    float a0 = bf2f(sw & 0xffffu);
    float a1 = bf2f(sw >> 16);
    int beg = rstart[v];
    int n = cnt[v];
    int j = 0;
    for (; j + 16 <= n; j += 16) {             // 16 edges: 2 idx/lane
        int ia = esrc[beg + j + 2 * q];
        int ib = esrc[beg + j + 2 * q + 1];
#pragma unroll
        for (int u = 0; u < 8; ++u) {
            int s0 = __shfl(ia, u, 8);
            int s1 = __shfl(ib, u, 8);
            unsigned a = base[(size_t)s0 * 8];
            unsigned c = base[(size_t)s1 * 8];
            a0 += bf2f(a & 0xffffu) + bf2f(c & 0xffffu);
            a1 += bf2f(a >> 16) + bf2f(c >> 16);
        }
    }
    if (j + 8 <= n) {                          // one 8-edge chunk
        int idx = esrc[beg + j + q];
#pragma unroll
        for (int u = 0; u < 8; ++u) {
            int s = __shfl(idx, u, 8);
            unsigned a = base[(size_t)s * 8];
            a0 += bf2f(a & 0xffffu);
            a1 += bf2f(a >> 16);
        }
        j += 8;
    }
    for (; j < n; ++j) {                       // tail: uniform load
        int s = esrc[beg + j];
        unsigned a = base[(size_t)s * 8];
        a0 += bf2f(a & 0xffffu);
        a1 += bf2f(a >> 16);
    }
    // exchange y within the 8-lane group (wave-local LDS, lockstep)
    int ln = threadIdx.x >> 3;
    ymat[ln][2 * q + 0] = a0;
    ymat[ln][2 * q + 1] = a1;
    float y[F0];
#pragma unroll
    for (int k = 0; k < F0; ++k) y[k] = ymat[ln][k];
    float d = dis[v];
    float p0 = 0.0f, p1 = 0.0f;
#pragma unroll
    for (int u = 0; u < 4; ++u) {
        int jf = q * 4 + u;                    // 32 features across 8 lanes x 4
        float s = 0.0f;
#pragma unroll
        for (int k = 0; k < F0; ++k) s = fmaf(y[k], w1[k * F1 + jf], s);
        float r = fmaxf(fmaf(d, s, bb[jf]), 0.0f);
        p0 = fmaf(r, w2[jf * F2 + 0], p0);
        p1 = fmaf(r, w2[jf * F2 + 1], p1);
    }
#pragma unroll
    for (int off = 1; off < 8; off <<= 1) {
        p0 += __shfl_xor(p0, off);
        p1 += __shfl_xor(p1, off);
    }
    if (q == 0) {
        g2[(size_t)v * F2 + 0] = d * p0;
        g2[(size_t)v * F2 + 1] = d * p1;
    }
}

// fused layer2 aggregate + output: 4 lanes per node, 8 gathers in flight
__global__ void k_out2(const float* __restrict__ g2, const int* __restrict__ cnt,
                       const int* __restrict__ rstart, const int* __restrict__ esrc,
                       const float* __restrict__ dis, const float* __restrict__ b2,
                       float* __restrict__ out, int N) {
    int t = blockIdx.x * blockDim.x + threadIdx.x;
    int v = t >> 2;
    int l = t & 3;
    if (v >= N) return;
    float o0 = 0.0f, o1 = 0.0f;
    int beg = rstart[v];
    int end = beg + cnt[v];
    int j = beg + l;
    for (; j + 28 < end; j += 32) {        // 8 independent gathers in flight
        int s0 = esrc[j];
        int s1 = esrc[j + 4];
        int s2 = esrc[j + 8];
        int s3 = esrc[j + 12];
        int s4 = esrc[j + 16];
        int s5 = esrc[j + 20];
        int s6 = esrc[j + 24];
        int s7 = esrc[j + 28];
        float2 a0 = *reinterpret_cast<const float2*>(g2 + (size_t)s0 * F2);
        float2 a1 = *reinterpret_cast<const float2*>(g2 + (size_t)s1 * F2);
        float2 a2 = *reinterpret_cast<const float2*>(g2 + (size_t)s2 * F2);
        float2 a3 = *reinterpret_cast<const float2*>(g2 + (size_t)s3 * F2);
        float2 a4 = *reinterpret_cast<const float2*>(g2 + (size_t)s4 * F2);
        float2 a5 = *reinterpret_cast<const float2*>(g2 + (size_t)s5 * F2);
        float2 a6 = *reinterpret_cast<const float2*>(g2 + (size_t)s6 * F2);
        float2 a7 = *reinterpret_cast<const float2*>(g2 + (size_t)s7 * F2);
        o0 += a0.x + a1.x + a2.x + a3.x + a4.x + a5.x + a6.x + a7.x;
        o1 += a0.y + a1.y + a2.y + a3.y + a4.y + a5.y + a6.y + a7.y;
    }
    for (; j + 12 < end; j += 16) {        // 4 in flight
        int s0 = esrc[j];
        int s1 = esrc[j + 4];
        int s2 = esrc[j + 8];
        int s3 = esrc[j + 12];
        float2 a0 = *reinterpret_cast<const float2*>(g2 + (size_t)s0 * F2);
        float2 a1 = *reinterpret_cast<const float2*>(g2 + (size_t)s1 * F2);
        float2 a2 = *reinterpret_cast<const float2*>(g2 + (size_t)s2 * F2);
        float2 a3 = *reinterpret_cast<const float2*>(g2 + (size_t)s3 * F2);
        o0 += a0.x + a1.x + a2.x + a3.x;
        o1 += a0.y + a1.y + a2.y + a3.y;
    }
    for (; j < end; j += 4) {
        int s = esrc[j];
        const float2 a = *reinterpret_cast<const float2*>(g2 + (size_t)s * F2);
        o0 += a.x; o1 += a.y;
    }
#pragma unroll
    for (int off = 1; off < 4; off <<= 1) {
        o0 += __shfl_xor(o0, off);
        o1 += __shfl_xor(o1, off);
    }
    if (l == 0) {
        float d = dis[v];
        const float2 self = *reinterpret_cast<const float2*>(g2 + (size_t)v * F2);
        out[(size_t)v * F2 + 0] = fmaf(d, o0 + self.x, b2[0]);
        out[(size_t)v * F2 + 1] = fmaf(d, o1 + self.y, b2[1]);
    }
}

extern "C" void kernel_launch(void* const* d_in, const int* in_sizes, int n_in,
                              void* d_out, int out_size, void* d_ws, size_t ws_size,
                              hipStream_t stream) {
    const float* x  = (const float*)d_in[0];
    const int* ei   = (const int*)d_in[1];
    const float* W1 = (const float*)d_in[2];
    const float* b1 = (const float*)d_in[3];
    const float* W2 = (const float*)d_in[4];
    const float* b2 = (const float*)d_in[5];
    float* out = (float*)d_out;

    const int N = in_sizes[0] / F0;          // 100000
    const int E = in_sizes[1] / 2;           // 3200000
    const int* src = ei;
    const int* dst = ei + E;
    const int nb = (N + BMSK) >> BSH;        // 196 buckets of 512 nodes
    const int nchunk = (E + EPB - 1) / EPB;  // 391 chunks

    // workspace layout (u32 units); pairs 16B-aligned
    unsigned* bfill = (unsigned*)d_ws;                    // MAXNB*BPAD (16KB)
    unsigned* pairs = bfill + MAXNB * BPAD;               // nb*CAP (~19.3MB)
    int* esrc       = (int*)(pairs + (size_t)nb * CAP);   // nb*CAP (~19.3MB)
    unsigned* xd    = (unsigned*)(esrc + (size_t)nb * CAP); // 8N (32B rows)
    float* dis      = (float*)(xd + (size_t)8 * N);       // N
    int* cnt        = (int*)(dis + N);                    // N
    int* rstart     = cnt + N;                            // N
    float* g2       = (float*)(rstart + N);               // 2N
    // total ~ 44 MB

    const int B = 256;
    const int nz = MAXNB * BPAD;
    k_zero<<<(nz + B - 1) / B, B, 0, stream>>>(bfill, nz);
    k_binA<<<nchunk, 512, 0, stream>>>(src, dst, bfill, pairs, E, nb);
    k_binB<<<nb, 1024, 0, stream>>>(pairs, bfill, x, cnt, dis, rstart, esrc, xd, N);
    k_layer1<<<(N * 8 + B - 1) / B, B, 0, stream>>>(xd, cnt, rstart, esrc, dis, b1, W1, W2, g2, N);
    k_out2<<<(N * 4 + B - 1) / B, B, 0, stream>>>(g2, cnt, rstart, esrc, dis, b2, out, N);
}

// Round 21
// 85.572 us; speedup vs baseline: 1.0897x; 1.0249x over previous
//
#include <hip/hip_runtime.h>

// GCN 2-layer, 5 dispatches:
//   zero: clear bfill (16KB) + dummy rows xd[N], g2[N]
//   binA: chunk-wise LDS counting sort of edges by dst-bucket (512 nodes),
//         register-stashed edges, 64B-aligned reservations into FIXED
//         per-bucket regions (b*CAP). 8-lane-group burst copy.
//   binB: one block per bucket, 1024 threads: uint4 hist pass -> wave scan
//         over roundup8(deg) -> cnt(padded)/dis/rstart/xd, pad slots filled
//         with dummy index N (zero row), pass2 scatter into 96KB LDS srt,
//         coalesced uint4 burst copy -> node-sorted esrc.
//   layer1: per-node 8-lane gather-aggregate of xd rows (32B, L2-resident),
//         16/8-edge chunks ONLY (edge lists padded to x8 -> no serial tail),
//         then in-register MLP -> g2
//   out2: per-node 4-lane gather-aggregate of g2 -> out, 8 gathers in flight
// norm trick: g = dis*(h@W); out[v] = dis[v]*(sum_{u->v} g[u] + g[v]) + b.

static constexpr int F0 = 16;
static constexpr int F1 = 32;
static constexpr int F2 = 2;
static constexpr int BSH  = 9;      // bucket = dst>>9 (512 nodes)
static constexpr int BMSK = 511;
static constexpr int NPB  = 512;    // nodes per bucket
static constexpr int MAXNB = 256;   // max coarse buckets (scan width)
static constexpr int NBMAX = 196;   // actual bucket count for N=100000
static constexpr int BPAD  = 16;    // cursor padded to own 64B line
static constexpr int EPB   = 8192;  // edges per binA chunk (= 16 per thread)
static constexpr int CAP   = 24576; // slots per bucket region
static constexpr int SORTCAP = EPB + NBMAX * 16;   // 11328 (~45KB)
static constexpr unsigned SENT = 0xFFFFFFFFu;

__device__ inline unsigned roundup16(unsigned h) { return (h + 15u) & ~15u; }
__device__ inline unsigned roundup8(unsigned h)  { return (h + 7u) & ~7u; }

__device__ inline unsigned f2bf(float f) {
    unsigned u = __float_as_uint(f);
    return (u + 0x7fffu + ((u >> 16) & 1u)) >> 16;   // RNE
}
__device__ inline float bf2f(unsigned b) {
    return __uint_as_float(b << 16);
}

// grid-stride zero + dummy-row clear (xd row N: 8 words; g2 row N: 2 words)
__global__ void k_zero(unsigned* __restrict__ p, int n,
                       unsigned* __restrict__ xdN, unsigned* __restrict__ g2N) {
    int i = blockIdx.x * blockDim.x + threadIdx.x;
    if (i < n) p[i] = 0u;
    if (i < 8) xdN[i] = 0u;
    if (i < 2) g2N[i] = 0u;
}

// LDS counting sort of a chunk (edges stashed in registers; one global read),
// then per-bucket 8-lane-group burst copy to global.
__global__ __launch_bounds__(512) void k_binA(const int* __restrict__ src,
                                              const int* __restrict__ dst,
                                              unsigned* __restrict__ bfill,
                                              unsigned* __restrict__ pairs,
                                              int E, int nb) {
    __shared__ unsigned h[MAXNB];
    __shared__ unsigned lbase[MAXNB];
    __shared__ unsigned bs_[MAXNB];
    __shared__ unsigned cur[MAXNB];
    __shared__ unsigned wsum[8];
    __shared__ unsigned wbase[8];
    __shared__ __attribute__((aligned(16))) unsigned sorted[SORTCAP];
    int tid = threadIdx.x;
    for (int b = tid; b < MAXNB; b += 512) { h[b] = 0; cur[b] = 0; }
    if (tid < 8) wsum[tid] = 0;
    __syncthreads();
    int e0 = blockIdx.x * EPB;
    int cn = min(EPB, E - e0);
    unsigned key[16];
    unsigned bkt[16];
#pragma unroll
    for (int j = 0; j < 16; ++j) {
        int idx = j * 512 + tid;
        if (idx < cn) {
            unsigned d = (unsigned)dst[e0 + idx];
            unsigned s = (unsigned)src[e0 + idx];
            unsigned b = d >> BSH;
            key[j] = (s << BSH) | (d & BMSK);
            bkt[j] = b;
            atomicAdd(&h[b], 1u);
        }
    }
    __syncthreads();
    // exclusive scan of roundup16(h) over 256 entries: wave shfl scan
    unsigned pv = 0, px = 0;
    if (tid < MAXNB) {
        pv = roundup16(h[tid]);
        px = pv;
#pragma unroll
        for (int off = 1; off < 64; off <<= 1) {
            unsigned t = __shfl_up(px, off, 64);
            if ((tid & 63) >= off) px += t;
        }
        if ((tid & 63) == 63) wsum[tid >> 6] = px;
    }
    __syncthreads();
    if (tid < 8) {
        unsigned acc = 0;
        for (int k = 0; k < tid; ++k) acc += wsum[k];
        wbase[tid] = acc;
    }
    __syncthreads();
    if (tid < MAXNB) {
        unsigned ex = px - pv + wbase[tid >> 6];
        lbase[tid] = ex;
        if (tid < nb && h[tid])
            bs_[tid] = (unsigned)(tid * CAP) + atomicAdd(&bfill[tid * BPAD], roundup16(h[tid]));
    }
    __syncthreads();
    // scatter from registers into LDS (bucket-sorted)
#pragma unroll
    for (int j = 0; j < 16; ++j) {
        int idx = j * 512 + tid;
        if (idx < cn) {
            unsigned b = bkt[j];
            unsigned pos = lbase[b] + atomicAdd(&cur[b], 1u);
            sorted[pos] = key[j];
        }
    }
    // sentinel-fill ONLY the pad slots
    for (int b = tid; b < nb; b += 512) {
        unsigned hb = h[b];
        if (!hb) continue;
        unsigned k0 = lbase[b] + hb;
        unsigned k1 = lbase[b] + roundup16(hb);
        for (unsigned k = k0; k < k1; ++k) sorted[k] = SENT;
    }
    __syncthreads();
    // burst copy: 8-lane group per bucket (64 groups), uint4 contiguous stores
    int grp = tid >> 3;
    int ln8 = tid & 7;
    for (int b = grp; b < nb; b += 64) {
        unsigned np = roundup16(h[b]) >> 2;   // uint4 count
        if (!np) continue;
        const uint4* sp = reinterpret_cast<const uint4*>(&sorted[lbase[b]]);
        uint4* gp = reinterpret_cast<uint4*>(&pairs[bs_[b]]);
        for (unsigned k = ln8; k < np; k += 8) gp[k] = sp[k];
    }
}

// per-bucket (1024 threads): hist pass -> wave scan over roundup8(deg) ->
// cnt(padded)/dis/rstart/xd + dummy pad fill; pass2 scatter into 96KB LDS srt,
// coalesced uint4 burst -> esrc.
__global__ __launch_bounds__(1024) void k_binB(const unsigned* __restrict__ pairs,
                                               const unsigned* __restrict__ bfill,
                                               const float* __restrict__ x,
                                               int* __restrict__ cnt, float* __restrict__ dis,
                                               int* __restrict__ rstart, int* __restrict__ esrc,
                                               unsigned* __restrict__ xd, int N) {
    __shared__ unsigned h[NPB];
    __shared__ unsigned cur[NPB];    // scatter cursor (starts at padded excl scan)
    __shared__ unsigned wsum[8];
    __shared__ unsigned wbase[8];
    __shared__ unsigned tot_s;
    __shared__ __attribute__((aligned(16))) unsigned srt[CAP];   // 96KB node-sorted
    int tid = threadIdx.x, b = blockIdx.x;
    if (tid < NPB) h[tid] = 0;
    __syncthreads();
    int r0 = b * CAP;
    int n4 = (int)bfill[b * BPAD] >> 2;
    const uint4* p4 = reinterpret_cast<const uint4*>(pairs + r0);
    for (int i = tid; i < n4; i += 1024) {
        uint4 p = p4[i];
        if (p.x != SENT) atomicAdd(&h[p.x & BMSK], 1u);
        if (p.y != SENT) atomicAdd(&h[p.y & BMSK], 1u);
        if (p.z != SENT) atomicAdd(&h[p.z & BMSK], 1u);
        if (p.w != SENT) atomicAdd(&h[p.w & BMSK], 1u);
    }
    __syncthreads();
    // exclusive scan over roundup8(counts) (first 512 threads): wave shfl scan
    unsigned v = 0, pv = 0, x2 = 0;
    if (tid < NPB) {
        v = h[tid];
        pv = roundup8(v);
        x2 = pv;
#pragma unroll
        for (int off = 1; off < 64; off <<= 1) {
            unsigned t = __shfl_up(x2, off, 64);
            if ((tid & 63) >= off) x2 += t;
        }
        if ((tid & 63) == 63) wsum[tid >> 6] = x2;
    }
    __syncthreads();
    if (tid < 8) {
        unsigned acc = 0;
        for (int k = 0; k < tid; ++k) acc += wsum[k];
        wbase[tid] = acc;
    }
    __syncthreads();
    if (tid < NPB) {
        unsigned ex = x2 - pv + wbase[tid >> 6];
        cur[tid] = ex;               // real edges fill [ex, ex+v)
        if (tid == NPB - 1) tot_s = ex + pv;
        // dummy pad fill [ex+v, ex+pv): index N -> zero row
        for (unsigned k = ex + v; k < ex + pv; ++k) srt[k] = (unsigned)N;
        int node = (b << BSH) + tid;
        if (node < N) {
            float d = rsqrtf((float)(v + 1u));   // real degree for norm
            cnt[node] = (int)pv;                 // padded count for gather loops
            dis[node] = d;
            rstart[node] = r0 + (int)ex;
            const float4* xp = reinterpret_cast<const float4*>(x + (size_t)node * F0);
            unsigned pk[8];
#pragma unroll
            for (int q = 0; q < 4; ++q) {
                float4 vv = xp[q];
                pk[2 * q + 0] = f2bf(d * vv.x) | (f2bf(d * vv.y) << 16);
                pk[2 * q + 1] = f2bf(d * vv.z) | (f2bf(d * vv.w) << 16);
            }
            uint4* o = reinterpret_cast<uint4*>(xd + (size_t)node * 8);
            o[0] = make_uint4(pk[0], pk[1], pk[2], pk[3]);
            o[1] = make_uint4(pk[4], pk[5], pk[6], pk[7]);
        }
    }
    __syncthreads();
    // pass2: re-read pairs (L2-warm), scatter into LDS srt (on-chip)
    for (int i = tid; i < n4; i += 1024) {
        uint4 p = p4[i];
        if (p.x != SENT) { unsigned o_ = atomicAdd(&cur[p.x & BMSK], 1u); srt[o_] = p.x >> BSH; }
        if (p.y != SENT) { unsigned o_ = atomicAdd(&cur[p.y & BMSK], 1u); srt[o_] = p.y >> BSH; }
        if (p.z != SENT) { unsigned o_ = atomicAdd(&cur[p.z & BMSK], 1u); srt[o_] = p.z >> BSH; }
        if (p.w != SENT) { unsigned o_ = atomicAdd(&cur[p.w & BMSK], 1u); srt[o_] = p.w >> BSH; }
    }
    __syncthreads();
    // coalesced burst copy srt -> esrc (uint4; tot_s is multiple of 8)
    unsigned tot4 = tot_s >> 2;
    const uint4* s4 = reinterpret_cast<const uint4*>(srt);
    uint4* g4 = reinterpret_cast<uint4*>(esrc + r0);
    for (unsigned k = tid; k < tot4; k += 1024) g4[k] = s4[k];
}

// fused layer1: 8 lanes/node gather-aggregate xd (1 u32/lane = 32B/row),
// 16/8-edge chunks only (padded lists) -> no serial tail; in-register MLP.
__global__ void k_layer1(const unsigned* __restrict__ xd, const int* __restrict__ cnt,
                         const int* __restrict__ rstart, const int* __restrict__ esrc,
                         const float* __restrict__ dis, const float* __restrict__ b1,
                         const float* __restrict__ W1, const float* __restrict__ W2,
                         float* __restrict__ g2, int N) {
    __shared__ float w1[F0 * F1];
    __shared__ float w2[F1 * F2];
    __shared__ float bb[F1];
    __shared__ float ymat[32][17];   // 32 nodes/block, +1 pad
    for (int j = threadIdx.x; j < F0 * F1; j += blockDim.x) w1[j] = W1[j];
    for (int j = threadIdx.x; j < F1 * F2; j += blockDim.x) w2[j] = W2[j];
    for (int j = threadIdx.x; j < F1; j += blockDim.x) bb[j] = b1[j];
    __syncthreads();
    int t = blockIdx.x * blockDim.x + threadIdx.x;
    int v = t >> 3;
    int q = t & 7;
    if (v >= N) return;
    const unsigned* base = xd + q;             // row stride 8 u32
    unsigned sw = base[(size_t)v * 8];         // self loop xd[v]
    float a0 = bf2f(sw & 0xffffu);
    float a1 = bf2f(sw >> 16);
    int beg = rstart[v];
    int n = cnt[v];                            // multiple of 8
    int j = 0;
    for (; j + 16 <= n; j += 16) {             // 16 edges: 2 idx/lane
        int ia = esrc[beg + j + 2 * q];
        int ib = esrc[beg + j + 2 * q + 1];
#pragma unroll
        for (int u = 0; u < 8; ++u) {
            int s0 = __shfl(ia, u, 8);
            int s1 = __shfl(ib, u, 8);
            unsigned a = base[(size_t)s0 * 8];
            unsigned c = base[(size_t)s1 * 8];
            a0 += bf2f(a & 0xffffu) + bf2f(c & 0xffffu);
            a1 += bf2f(a >> 16) + bf2f(c >> 16);
        }
    }
    if (j < n) {                               // exactly one 8-edge chunk
        int idx = esrc[beg + j + q];
#pragma unroll
        for (int u = 0; u < 8; ++u) {
            int s = __shfl(idx, u, 8);
            unsigned a = base[(size_t)s * 8];
            a0 += bf2f(a & 0xffffu);
            a1 += bf2f(a >> 16);
        }
    }
    // exchange y within the 8-lane group (wave-local LDS, lockstep)
    int ln = threadIdx.x >> 3;
    ymat[ln][2 * q + 0] = a0;
    ymat[ln][2 * q + 1] = a1;
    float y[F0];
#pragma unroll
    for (int k = 0; k < F0; ++k) y[k] = ymat[ln][k];
    float d = dis[v];
    float p0 = 0.0f, p1 = 0.0f;
#pragma unroll
    for (int u = 0; u < 4; ++u) {
        int jf = q * 4 + u;                    // 32 features across 8 lanes x 4
        float s = 0.0f;
#pragma unroll
        for (int k = 0; k < F0; ++k) s = fmaf(y[k], w1[k * F1 + jf], s);
        float r = fmaxf(fmaf(d, s, bb[jf]), 0.0f);
        p0 = fmaf(r, w2[jf * F2 + 0], p0);
        p1 = fmaf(r, w2[jf * F2 + 1], p1);
    }
#pragma unroll
    for (int off = 1; off < 8; off <<= 1) {
        p0 += __shfl_xor(p0, off);
        p1 += __shfl_xor(p1, off);
    }
    if (q == 0) {
        g2[(size_t)v * F2 + 0] = d * p0;
        g2[(size_t)v * F2 + 1] = d * p1;
    }
}

// fused layer2 aggregate + output: 4 lanes per node, 8 gathers in flight
__global__ void k_out2(const float* __restrict__ g2, const int* __restrict__ cnt,
                       const int* __restrict__ rstart, const int* __restrict__ esrc,
                       const float* __restrict__ dis, const float* __restrict__ b2,
                       float* __restrict__ out, int N) {
    int t = blockIdx.x * blockDim.x + threadIdx.x;
    int v = t >> 2;
    int l = t & 3;
    if (v >= N) return;
    float o0 = 0.0f, o1 = 0.0f;
    int beg = rstart[v];
    int end = beg + cnt[v];              // padded; dummies gather g2[N]=0
    int j = beg + l;
    for (; j + 28 < end; j += 32) {      // 8 independent gathers in flight
        int s0 = esrc[j];
        int s1 = esrc[j + 4];
        int s2 = esrc[j + 8];
        int s3 = esrc[j + 12];
        int s4 = esrc[j + 16];
        int s5 = esrc[j + 20];
        int s6 = esrc[j + 24];
        int s7 = esrc[j + 28];
        float2 a0 = *reinterpret_cast<const float2*>(g2 + (size_t)s0 * F2);
        float2 a1 = *reinterpret_cast<const float2*>(g2 + (size_t)s1 * F2);
        float2 a2 = *reinterpret_cast<const float2*>(g2 + (size_t)s2 * F2);
        float2 a3 = *reinterpret_cast<const float2*>(g2 + (size_t)s3 * F2);
        float2 a4 = *reinterpret_cast<const float2*>(g2 + (size_t)s4 * F2);
        float2 a5 = *reinterpret_cast<const float2*>(g2 + (size_t)s5 * F2);
        float2 a6 = *reinterpret_cast<const float2*>(g2 + (size_t)s6 * F2);
        float2 a7 = *reinterpret_cast<const float2*>(g2 + (size_t)s7 * F2);
        o0 += a0.x + a1.x + a2.x + a3.x + a4.x + a5.x + a6.x + a7.x;
        o1 += a0.y + a1.y + a2.y + a3.y + a4.y + a5.y + a6.y + a7.y;
    }
    for (; j + 12 < end; j += 16) {      // 4 in flight
        int s0 = esrc[j];
        int s1 = esrc[j + 4];
        int s2 = esrc[j + 8];
        int s3 = esrc[j + 12];
        float2 a0 = *reinterpret_cast<const float2*>(g2 + (size_t)s0 * F2);
        float2 a1 = *reinterpret_cast<const float2*>(g2 + (size_t)s1 * F2);
        float2 a2 = *reinterpret_cast<const float2*>(g2 + (size_t)s2 * F2);
        float2 a3 = *reinterpret_cast<const float2*>(g2 + (size_t)s3 * F2);
        o0 += a0.x + a1.x + a2.x + a3.x;
        o1 += a0.y + a1.y + a2.y + a3.y;
    }
    for (; j < end; j += 4) {
        int s = esrc[j];
        const float2 a = *reinterpret_cast<const float2*>(g2 + (size_t)s * F2);
        o0 += a.x; o1 += a.y;
    }
#pragma unroll
    for (int off = 1; off < 4; off <<= 1) {
        o0 += __shfl_xor(o0, off);
        o1 += __shfl_xor(o1, off);
    }
    if (l == 0) {
        float d = dis[v];
        const float2 self = *reinterpret_cast<const float2*>(g2 + (size_t)v * F2);
        out[(size_t)v * F2 + 0] = fmaf(d, o0 + self.x, b2[0]);
        out[(size_t)v * F2 + 1] = fmaf(d, o1 + self.y, b2[1]);
    }
}

extern "C" void kernel_launch(void* const* d_in, const int* in_sizes, int n_in,
                              void* d_out, int out_size, void* d_ws, size_t ws_size,
                              hipStream_t stream) {
    const float* x  = (const float*)d_in[0];
    const int* ei   = (const int*)d_in[1];
    const float* W1 = (const float*)d_in[2];
    const float* b1 = (const float*)d_in[3];
    const float* W2 = (const float*)d_in[4];
    const float* b2 = (const float*)d_in[5];
    float* out = (float*)d_out;

    const int N = in_sizes[0] / F0;          // 100000
    const int E = in_sizes[1] / 2;           // 3200000
    const int* src = ei;
    const int* dst = ei + E;
    const int nb = (N + BMSK) >> BSH;        // 196 buckets of 512 nodes
    const int nchunk = (E + EPB - 1) / EPB;  // 391 chunks

    // workspace layout (u32 units); pairs 16B-aligned
    unsigned* bfill = (unsigned*)d_ws;                    // MAXNB*BPAD (16KB)
    unsigned* pairs = bfill + MAXNB * BPAD;               // nb*CAP (~19.3MB)
    int* esrc       = (int*)(pairs + (size_t)nb * CAP);   // nb*CAP (~19.3MB)
    unsigned* xd    = (unsigned*)(esrc + (size_t)nb * CAP); // 8*(N+1) (32B rows + dummy)
    float* dis      = (float*)(xd + (size_t)8 * (N + 1)); // N
    int* cnt        = (int*)(dis + N);                    // N
    int* rstart     = cnt + N;                            // N
    float* g2       = (float*)(rstart + N);               // 2*(N+1)
    // total ~ 44 MB

    const int B = 256;
    const int nz = MAXNB * BPAD;
    k_zero<<<(nz + B - 1) / B, B, 0, stream>>>(bfill, nz,
                                               xd + (size_t)8 * N,
                                               (unsigned*)(g2 + (size_t)2 * N));
    k_binA<<<nchunk, 512, 0, stream>>>(src, dst, bfill, pairs, E, nb);
    k_binB<<<nb, 1024, 0, stream>>>(pairs, bfill, x, cnt, dis, rstart, esrc, xd, N);
    k_layer1<<<(N * 8 + B - 1) / B, B, 0, stream>>>(xd, cnt, rstart, esrc, dis, b1, W1, W2, g2, N);
    k_out2<<<(N * 4 + B - 1) / B, B, 0, stream>>>(g2, cnt, rstart, esrc, dis, b2, out, N);
}

// Round 22
// 85.399 us; speedup vs baseline: 1.0919x; 1.0020x over previous
//
#include <hip/hip_runtime.h>

// GCN 2-layer, 5 dispatches:
//   zero: clear bfill (16KB) + dummy rows xd[N], g2[N]
//   binA: chunk-wise LDS counting sort of edges by dst-bucket (512 nodes),
//         register-stashed edges, 64B-aligned reservations into FIXED
//         per-bucket regions (b*CAP). 8-lane-group burst copy.
//   binB: one block per bucket, 1024 threads, SINGLE pass over pairs:
//         region register-stashed (6 uint4/thread) -> hist -> wave scan over
//         roundup8(deg) -> cnt(padded)/dis/rstart/xd + dummy pad fill ->
//         scatter from registers into 96KB LDS srt -> uint4 burst -> esrc.
//   layer1: per-node 8-lane gather-aggregate of xd rows (32B, L2-resident),
//         16/8-edge chunks ONLY (edge lists padded to x8 -> no serial tail),
//         then in-register MLP -> g2
//   out2: per-node 4-lane gather-aggregate of g2 -> out, 8 gathers in flight
// norm trick: g = dis*(h@W); out[v] = dis[v]*(sum_{u->v} g[u] + g[v]) + b.

static constexpr int F0 = 16;
static constexpr int F1 = 32;
static constexpr int F2 = 2;
static constexpr int BSH  = 9;      // bucket = dst>>9 (512 nodes)
static constexpr int BMSK = 511;
static constexpr int NPB  = 512;    // nodes per bucket
static constexpr int MAXNB = 256;   // max coarse buckets (scan width)
static constexpr int NBMAX = 196;   // actual bucket count for N=100000
static constexpr int BPAD  = 16;    // cursor padded to own 64B line
static constexpr int EPB   = 8192;  // edges per binA chunk (= 16 per thread)
static constexpr int CAP   = 24576; // slots per bucket region (= 6144 uint4)
static constexpr int SORTCAP = EPB + NBMAX * 16;   // 11328 (~45KB)
static constexpr unsigned SENT = 0xFFFFFFFFu;

__device__ inline unsigned roundup16(unsigned h) { return (h + 15u) & ~15u; }
__device__ inline unsigned roundup8(unsigned h)  { return (h + 7u) & ~7u; }

__device__ inline unsigned f2bf(float f) {
    unsigned u = __float_as_uint(f);
    return (u + 0x7fffu + ((u >> 16) & 1u)) >> 16;   // RNE
}
__device__ inline float bf2f(unsigned b) {
    return __uint_as_float(b << 16);
}

// grid-stride zero + dummy-row clear (xd row N: 8 words; g2 row N: 2 words)
__global__ void k_zero(unsigned* __restrict__ p, int n,
                       unsigned* __restrict__ xdN, unsigned* __restrict__ g2N) {
    int i = blockIdx.x * blockDim.x + threadIdx.x;
    if (i < n) p[i] = 0u;
    if (i < 8) xdN[i] = 0u;
    if (i < 2) g2N[i] = 0u;
}

// LDS counting sort of a chunk (edges stashed in registers; one global read),
// then per-bucket 8-lane-group burst copy to global.
__global__ __launch_bounds__(512) void k_binA(const int* __restrict__ src,
                                              const int* __restrict__ dst,
                                              unsigned* __restrict__ bfill,
                                              unsigned* __restrict__ pairs,
                                              int E, int nb) {
    __shared__ unsigned h[MAXNB];
    __shared__ unsigned lbase[MAXNB];
    __shared__ unsigned bs_[MAXNB];
    __shared__ unsigned cur[MAXNB];
    __shared__ unsigned wsum[8];
    __shared__ unsigned wbase[8];
    __shared__ __attribute__((aligned(16))) unsigned sorted[SORTCAP];
    int tid = threadIdx.x;
    for (int b = tid; b < MAXNB; b += 512) { h[b] = 0; cur[b] = 0; }
    if (tid < 8) wsum[tid] = 0;
    __syncthreads();
    int e0 = blockIdx.x * EPB;
    int cn = min(EPB, E - e0);
    unsigned key[16];
    unsigned bkt[16];
#pragma unroll
    for (int j = 0; j < 16; ++j) {
        int idx = j * 512 + tid;
        if (idx < cn) {
            unsigned d = (unsigned)dst[e0 + idx];
            unsigned s = (unsigned)src[e0 + idx];
            unsigned b = d >> BSH;
            key[j] = (s << BSH) | (d & BMSK);
            bkt[j] = b;
            atomicAdd(&h[b], 1u);
        }
    }
    __syncthreads();
    // exclusive scan of roundup16(h) over 256 entries: wave shfl scan
    unsigned pv = 0, px = 0;
    if (tid < MAXNB) {
        pv = roundup16(h[tid]);
        px = pv;
#pragma unroll
        for (int off = 1; off < 64; off <<= 1) {
            unsigned t = __shfl_up(px, off, 64);
            if ((tid & 63) >= off) px += t;
        }
        if ((tid & 63) == 63) wsum[tid >> 6] = px;
    }
    __syncthreads();
    if (tid < 8) {
        unsigned acc = 0;
        for (int k = 0; k < tid; ++k) acc += wsum[k];
        wbase[tid] = acc;
    }
    __syncthreads();
    if (tid < MAXNB) {
        unsigned ex = px - pv + wbase[tid >> 6];
        lbase[tid] = ex;
        if (tid < nb && h[tid])
            bs_[tid] = (unsigned)(tid * CAP) + atomicAdd(&bfill[tid * BPAD], roundup16(h[tid]));
    }
    __syncthreads();
    // scatter from registers into LDS (bucket-sorted)
#pragma unroll
    for (int j = 0; j < 16; ++j) {
        int idx = j * 512 + tid;
        if (idx < cn) {
            unsigned b = bkt[j];
            unsigned pos = lbase[b] + atomicAdd(&cur[b], 1u);
            sorted[pos] = key[j];
        }
    }
    // sentinel-fill ONLY the pad slots
    for (int b = tid; b < nb; b += 512) {
        unsigned hb = h[b];
        if (!hb) continue;
        unsigned k0 = lbase[b] + hb;
        unsigned k1 = lbase[b] + roundup16(hb);
        for (unsigned k = k0; k < k1; ++k) sorted[k] = SENT;
    }
    __syncthreads();
    // burst copy: 8-lane group per bucket (64 groups), uint4 contiguous stores
    int grp = tid >> 3;
    int ln8 = tid & 7;
    for (int b = grp; b < nb; b += 64) {
        unsigned np = roundup16(h[b]) >> 2;   // uint4 count
        if (!np) continue;
        const uint4* sp = reinterpret_cast<const uint4*>(&sorted[lbase[b]]);
        uint4* gp = reinterpret_cast<uint4*>(&pairs[bs_[b]]);
        for (unsigned k = ln8; k < np; k += 8) gp[k] = sp[k];
    }
}

// per-bucket (1024 threads), SINGLE global pass: register-stash pairs ->
// hist -> wave scan over roundup8(deg) -> cnt/dis/rstart/xd + dummy pads ->
// scatter from registers into 96KB LDS srt -> coalesced uint4 burst -> esrc.
__global__ __launch_bounds__(1024) void k_binB(const unsigned* __restrict__ pairs,
                                               const unsigned* __restrict__ bfill,
                                               const float* __restrict__ x,
                                               int* __restrict__ cnt, float* __restrict__ dis,
                                               int* __restrict__ rstart, int* __restrict__ esrc,
                                               unsigned* __restrict__ xd, int N) {
    __shared__ unsigned h[NPB];
    __shared__ unsigned cur[NPB];    // scatter cursor (starts at padded excl scan)
    __shared__ unsigned wsum[8];
    __shared__ unsigned wbase[8];
    __shared__ unsigned tot_s;
    __shared__ __attribute__((aligned(16))) unsigned srt[CAP];   // 96KB node-sorted
    int tid = threadIdx.x, b = blockIdx.x;
    if (tid < NPB) h[tid] = 0;
    __syncthreads();
    int r0 = b * CAP;
    int n4 = (int)bfill[b * BPAD] >> 2;
    const uint4* p4 = reinterpret_cast<const uint4*>(pairs + r0);
    uint4 rs[6];                     // 6*1024 = 6144 uint4 = CAP exactly
#pragma unroll
    for (int k = 0; k < 6; ++k) {
        int idx = k * 1024 + tid;
        if (idx < n4) {
            rs[k] = p4[idx];
            uint4 p = rs[k];
            if (p.x != SENT) atomicAdd(&h[p.x & BMSK], 1u);
            if (p.y != SENT) atomicAdd(&h[p.y & BMSK], 1u);
            if (p.z != SENT) atomicAdd(&h[p.z & BMSK], 1u);
            if (p.w != SENT) atomicAdd(&h[p.w & BMSK], 1u);
        }
    }
    __syncthreads();
    // exclusive scan over roundup8(counts) (first 512 threads): wave shfl scan
    unsigned v = 0, pv = 0, x2 = 0;
    if (tid < NPB) {
        v = h[tid];
        pv = roundup8(v);
        x2 = pv;
#pragma unroll
        for (int off = 1; off < 64; off <<= 1) {
            unsigned t = __shfl_up(x2, off, 64);
            if ((tid & 63) >= off) x2 += t;
        }
        if ((tid & 63) == 63) wsum[tid >> 6] = x2;
    }
    __syncthreads();
    if (tid < 8) {
        unsigned acc = 0;
        for (int k = 0; k < tid; ++k) acc += wsum[k];
        wbase[tid] = acc;
    }
    __syncthreads();
    if (tid < NPB) {
        unsigned ex = x2 - pv + wbase[tid >> 6];
        cur[tid] = ex;               // real edges fill [ex, ex+v)
        if (tid == NPB - 1) tot_s = ex + pv;
        // dummy pad fill [ex+v, ex+pv): index N -> zero row
        for (unsigned k = ex + v; k < ex + pv; ++k) srt[k] = (unsigned)N;
        int node = (b << BSH) + tid;
        if (node < N) {
            float d = rsqrtf((float)(v + 1u));   // real degree for norm
            cnt[node] = (int)pv;                 // padded count for gather loops
            dis[node] = d;
            rstart[node] = r0 + (int)ex;
            const float4* xp = reinterpret_cast<const float4*>(x + (size_t)node * F0);
            unsigned pk[8];
#pragma unroll
            for (int q = 0; q < 4; ++q) {
                float4 vv = xp[q];
                pk[2 * q + 0] = f2bf(d * vv.x) | (f2bf(d * vv.y) << 16);
                pk[2 * q + 1] = f2bf(d * vv.z) | (f2bf(d * vv.w) << 16);
            }
            uint4* o = reinterpret_cast<uint4*>(xd + (size_t)node * 8);
            o[0] = make_uint4(pk[0], pk[1], pk[2], pk[3]);
            o[1] = make_uint4(pk[4], pk[5], pk[6], pk[7]);
        }
    }
    __syncthreads();
    // scatter from REGISTERS into LDS srt (no second global pass)
#pragma unroll
    for (int k = 0; k < 6; ++k) {
        int idx = k * 1024 + tid;
        if (idx < n4) {
            uint4 p = rs[k];
            if (p.x != SENT) { unsigned o_ = atomicAdd(&cur[p.x & BMSK], 1u); srt[o_] = p.x >> BSH; }
            if (p.y != SENT) { unsigned o_ = atomicAdd(&cur[p.y & BMSK], 1u); srt[o_] = p.y >> BSH; }
            if (p.z != SENT) { unsigned o_ = atomicAdd(&cur[p.z & BMSK], 1u); srt[o_] = p.z >> BSH; }
            if (p.w != SENT) { unsigned o_ = atomicAdd(&cur[p.w & BMSK], 1u); srt[o_] = p.w >> BSH; }
        }
    }
    __syncthreads();
    // coalesced burst copy srt -> esrc (uint4; tot_s is multiple of 8)
    unsigned tot4 = tot_s >> 2;
    const uint4* s4 = reinterpret_cast<const uint4*>(srt);
    uint4* g4 = reinterpret_cast<uint4*>(esrc + r0);
    for (unsigned k = tid; k < tot4; k += 1024) g4[k] = s4[k];
}

// fused layer1: 8 lanes/node gather-aggregate xd (1 u32/lane = 32B/row),
// 16/8-edge chunks only (padded lists) -> no serial tail; in-register MLP.
__global__ void k_layer1(const unsigned* __restrict__ xd, const int* __restrict__ cnt,
                         const int* __restrict__ rstart, const int* __restrict__ esrc,
                         const float* __restrict__ dis, const float* __restrict__ b1,
                         const float* __restrict__ W1, const float* __restrict__ W2,
                         float* __restrict__ g2, int N) {
    __shared__ float w1[F0 * F1];
    __shared__ float w2[F1 * F2];
    __shared__ float bb[F1];
    __shared__ float ymat[32][17];   // 32 nodes/block, +1 pad
    for (int j = threadIdx.x; j < F0 * F1; j += blockDim.x) w1[j] = W1[j];
    for (int j = threadIdx.x; j < F1 * F2; j += blockDim.x) w2[j] = W2[j];
    for (int j = threadIdx.x; j < F1; j += blockDim.x) bb[j] = b1[j];
    __syncthreads();
    int t = blockIdx.x * blockDim.x + threadIdx.x;
    int v = t >> 3;
    int q = t & 7;
    if (v >= N) return;
    const unsigned* base = xd + q;             // row stride 8 u32
    unsigned sw = base[(size_t)v * 8];         // self loop xd[v]
    float a0 = bf2f(sw & 0xffffu);
    float a1 = bf2f(sw >> 16);
    int beg = rstart[v];
    int n = cnt[v];                            // multiple of 8
    int j = 0;
    for (; j + 16 <= n; j += 16) {             // 16 edges: 2 idx/lane
        int ia = esrc[beg + j + 2 * q];
        int ib = esrc[beg + j + 2 * q + 1];
#pragma unroll
        for (int u = 0; u < 8; ++u) {
            int s0 = __shfl(ia, u, 8);
            int s1 = __shfl(ib, u, 8);
            unsigned a = base[(size_t)s0 * 8];
            unsigned c = base[(size_t)s1 * 8];
            a0 += bf2f(a & 0xffffu) + bf2f(c & 0xffffu);
            a1 += bf2f(a >> 16) + bf2f(c >> 16);
        }
    }
    if (j < n) {                               // exactly one 8-edge chunk
        int idx = esrc[beg + j + q];
#pragma unroll
        for (int u = 0; u < 8; ++u) {
            int s = __shfl(idx, u, 8);
            unsigned a = base[(size_t)s * 8];
            a0 += bf2f(a & 0xffffu);
            a1 += bf2f(a >> 16);
        }
    }
    // exchange y within the 8-lane group (wave-local LDS, lockstep)
    int ln = threadIdx.x >> 3;
    ymat[ln][2 * q + 0] = a0;
    ymat[ln][2 * q + 1] = a1;
    float y[F0];
#pragma unroll
    for (int k = 0; k < F0; ++k) y[k] = ymat[ln][k];
    float d = dis[v];
    float p0 = 0.0f, p1 = 0.0f;
#pragma unroll
    for (int u = 0; u < 4; ++u) {
        int jf = q * 4 + u;                    // 32 features across 8 lanes x 4
        float s = 0.0f;
#pragma unroll
        for (int k = 0; k < F0; ++k) s = fmaf(y[k], w1[k * F1 + jf], s);
        float r = fmaxf(fmaf(d, s, bb[jf]), 0.0f);
        p0 = fmaf(r, w2[jf * F2 + 0], p0);
        p1 = fmaf(r, w2[jf * F2 + 1], p1);
    }
#pragma unroll
    for (int off = 1; off < 8; off <<= 1) {
        p0 += __shfl_xor(p0, off);
        p1 += __shfl_xor(p1, off);
    }
    if (q == 0) {
        g2[(size_t)v * F2 + 0] = d * p0;
        g2[(size_t)v * F2 + 1] = d * p1;
    }
}

// fused layer2 aggregate + output: 4 lanes per node, 8 gathers in flight
__global__ void k_out2(const float* __restrict__ g2, const int* __restrict__ cnt,
                       const int* __restrict__ rstart, const int* __restrict__ esrc,
                       const float* __restrict__ dis, const float* __restrict__ b2,
                       float* __restrict__ out, int N) {
    int t = blockIdx.x * blockDim.x + threadIdx.x;
    int v = t >> 2;
    int l = t & 3;
    if (v >= N) return;
    float o0 = 0.0f, o1 = 0.0f;
    int beg = rstart[v];
    int end = beg + cnt[v];              // padded; dummies gather g2[N]=0
    int j = beg + l;
    for (; j + 28 < end; j += 32) {      // 8 independent gathers in flight
        int s0 = esrc[j];
        int s1 = esrc[j + 4];
        int s2 = esrc[j + 8];
        int s3 = esrc[j + 12];
        int s4 = esrc[j + 16];
        int s5 = esrc[j + 20];
        int s6 = esrc[j + 24];
        int s7 = esrc[j + 28];
        float2 a0 = *reinterpret_cast<const float2*>(g2 + (size_t)s0 * F2);
        float2 a1 = *reinterpret_cast<const float2*>(g2 + (size_t)s1 * F2);
        float2 a2 = *reinterpret_cast<const float2*>(g2 + (size_t)s2 * F2);
        float2 a3 = *reinterpret_cast<const float2*>(g2 + (size_t)s3 * F2);
        float2 a4 = *reinterpret_cast<const float2*>(g2 + (size_t)s4 * F2);
        float2 a5 = *reinterpret_cast<const float2*>(g2 + (size_t)s5 * F2);
        float2 a6 = *reinterpret_cast<const float2*>(g2 + (size_t)s6 * F2);
        float2 a7 = *reinterpret_cast<const float2*>(g2 + (size_t)s7 * F2);
        o0 += a0.x + a1.x + a2.x + a3.x + a4.x + a5.x + a6.x + a7.x;
        o1 += a0.y + a1.y + a2.y + a3.y + a4.y + a5.y + a6.y + a7.y;
    }
    for (; j + 12 < end; j += 16) {      // 4 in flight
        int s0 = esrc[j];
        int s1 = esrc[j + 4];
        int s2 = esrc[j + 8];
        int s3 = esrc[j + 12];
        float2 a0 = *reinterpret_cast<const float2*>(g2 + (size_t)s0 * F2);
        float2 a1 = *reinterpret_cast<const float2*>(g2 + (size_t)s1 * F2);
        float2 a2 = *reinterpret_cast<const float2*>(g2 + (size_t)s2 * F2);
        float2 a3 = *reinterpret_cast<const float2*>(g2 + (size_t)s3 * F2);
        o0 += a0.x + a1.x + a2.x + a3.x;
        o1 += a0.y + a1.y + a2.y + a3.y;
    }
    for (; j < end; j += 4) {
        int s = esrc[j];
        const float2 a = *reinterpret_cast<const float2*>(g2 + (size_t)s * F2);
        o0 += a.x; o1 += a.y;
    }
#pragma unroll
    for (int off = 1; off < 4; off <<= 1) {
        o0 += __shfl_xor(o0, off);
        o1 += __shfl_xor(o1, off);
    }
    if (l == 0) {
        float d = dis[v];
        const float2 self = *reinterpret_cast<const float2*>(g2 + (size_t)v * F2);
        out[(size_t)v * F2 + 0] = fmaf(d, o0 + self.x, b2[0]);
        out[(size_t)v * F2 + 1] = fmaf(d, o1 + self.y, b2[1]);
    }
}

extern "C" void kernel_launch(void* const* d_in, const int* in_sizes, int n_in,
                              void* d_out, int out_size, void* d_ws, size_t ws_size,
                              hipStream_t stream) {
    const float* x  = (const float*)d_in[0];
    const int* ei   = (const int*)d_in[1];
    const float* W1 = (const float*)d_in[2];
    const float* b1 = (const float*)d_in[3];
    const float* W2 = (const float*)d_in[4];
    const float* b2 = (const float*)d_in[5];
    float* out = (float*)d_out;

    const int N = in_sizes[0] / F0;          // 100000
    const int E = in_sizes[1] / 2;           // 3200000
    const int* src = ei;
    const int* dst = ei + E;
    const int nb = (N + BMSK) >> BSH;        // 196 buckets of 512 nodes
    const int nchunk = (E + EPB - 1) / EPB;  // 391 chunks

    // workspace layout (u32 units); pairs 16B-aligned
    unsigned* bfill = (unsigned*)d_ws;                    // MAXNB*BPAD (16KB)
    unsigned* pairs = bfill + MAXNB * BPAD;               // nb*CAP (~19.3MB)
    int* esrc       = (int*)(pairs + (size_t)nb * CAP);   // nb*CAP (~19.3MB)
    unsigned* xd    = (unsigned*)(esrc + (size_t)nb * CAP); // 8*(N+1) (32B rows + dummy)
    float* dis      = (float*)(xd + (size_t)8 * (N + 1)); // N
    int* cnt        = (int*)(dis + N);                    // N
    int* rstart     = cnt + N;                            // N
    float* g2       = (float*)(rstart + N);               // 2*(N+1)
    // total ~ 44 MB

    const int B = 256;
    const int nz = MAXNB * BPAD;
    k_zero<<<(nz + B - 1) / B, B, 0, stream>>>(bfill, nz,
                                               xd + (size_t)8 * N,
                                               (unsigned*)(g2 + (size_t)2 * N));
    k_binA<<<nchunk, 512, 0, stream>>>(src, dst, bfill, pairs, E, nb);
    k_binB<<<nb, 1024, 0, stream>>>(pairs, bfill, x, cnt, dis, rstart, esrc, xd, N);
    k_layer1<<<(N * 8 + B - 1) / B, B, 0, stream>>>(xd, cnt, rstart, esrc, dis, b1, W1, W2, g2, N);
    k_out2<<<(N * 4 + B - 1) / B, B, 0, stream>>>(g2, cnt, rstart, esrc, dis, b2, out, N);
}

// Round 23
// 85.374 us; speedup vs baseline: 1.0922x; 1.0003x over previous
//
#include <hip/hip_runtime.h>

// GCN 2-layer, 5 dispatches:
//   zero: clear bfill (16KB) + dummy rows xd[N], g2[N]
//   binA: chunk-wise LDS counting sort of edges by dst-bucket (512 nodes),
//         register-stashed edges, 64B-aligned reservations into FIXED
//         per-bucket regions (b*CAP). 8-lane-group burst copy.
//   binB: one block per bucket, 1024 threads, SINGLE pass over pairs:
//         region register-stashed (6 uint4/thread) -> hist -> wave scan over
//         roundup8(deg) -> cnt(padded)/dis/rstart/xd + dummy pad fill ->
//         scatter from registers into 96KB LDS srt -> uint4 burst -> esrc.
//   layer1: per-node 8-lane gather-aggregate of xd rows (32B, L2-resident),
//         32/16/8-edge chunks (int4/int2 esrc loads; up to 32 gathers in
//         flight -> covers L2 latency), then in-register MLP -> g2
//   out2: per-node 4-lane gather-aggregate of g2 -> out, 8 gathers in flight
// norm trick: g = dis*(h@W); out[v] = dis[v]*(sum_{u->v} g[u] + g[v]) + b.

static constexpr int F0 = 16;
static constexpr int F1 = 32;
static constexpr int F2 = 2;
static constexpr int BSH  = 9;      // bucket = dst>>9 (512 nodes)
static constexpr int BMSK = 511;
static constexpr int NPB  = 512;    // nodes per bucket
static constexpr int MAXNB = 256;   // max coarse buckets (scan width)
static constexpr int NBMAX = 196;   // actual bucket count for N=100000
static constexpr int BPAD  = 16;    // cursor padded to own 64B line
static constexpr int EPB   = 8192;  // edges per binA chunk (= 16 per thread)
static constexpr int CAP   = 24576; // slots per bucket region (= 6144 uint4)
static constexpr int SORTCAP = EPB + NBMAX * 16;   // 11328 (~45KB)
static constexpr unsigned SENT = 0xFFFFFFFFu;

__device__ inline unsigned roundup16(unsigned h) { return (h + 15u) & ~15u; }
__device__ inline unsigned roundup8(unsigned h)  { return (h + 7u) & ~7u; }

__device__ inline unsigned f2bf(float f) {
    unsigned u = __float_as_uint(f);
    return (u + 0x7fffu + ((u >> 16) & 1u)) >> 16;   // RNE
}
__device__ inline float bf2f(unsigned b) {
    return __uint_as_float(b << 16);
}

// grid-stride zero + dummy-row clear (xd row N: 8 words; g2 row N: 2 words)
__global__ void k_zero(unsigned* __restrict__ p, int n,
                       unsigned* __restrict__ xdN, unsigned* __restrict__ g2N) {
    int i = blockIdx.x * blockDim.x + threadIdx.x;
    if (i < n) p[i] = 0u;
    if (i < 8) xdN[i] = 0u;
    if (i < 2) g2N[i] = 0u;
}

// LDS counting sort of a chunk (edges stashed in registers; one global read),
// then per-bucket 8-lane-group burst copy to global.
__global__ __launch_bounds__(512) void k_binA(const int* __restrict__ src,
                                              const int* __restrict__ dst,
                                              unsigned* __restrict__ bfill,
                                              unsigned* __restrict__ pairs,
                                              int E, int nb) {
    __shared__ unsigned h[MAXNB];
    __shared__ unsigned lbase[MAXNB];
    __shared__ unsigned bs_[MAXNB];
    __shared__ unsigned cur[MAXNB];
    __shared__ unsigned wsum[8];
    __shared__ unsigned wbase[8];
    __shared__ __attribute__((aligned(16))) unsigned sorted[SORTCAP];
    int tid = threadIdx.x;
    for (int b = tid; b < MAXNB; b += 512) { h[b] = 0; cur[b] = 0; }
    if (tid < 8) wsum[tid] = 0;
    __syncthreads();
    int e0 = blockIdx.x * EPB;
    int cn = min(EPB, E - e0);
    unsigned key[16];
    unsigned bkt[16];
#pragma unroll
    for (int j = 0; j < 16; ++j) {
        int idx = j * 512 + tid;
        if (idx < cn) {
            unsigned d = (unsigned)dst[e0 + idx];
            unsigned s = (unsigned)src[e0 + idx];
            unsigned b = d >> BSH;
            key[j] = (s << BSH) | (d & BMSK);
            bkt[j] = b;
            atomicAdd(&h[b], 1u);
        }
    }
    __syncthreads();
    // exclusive scan of roundup16(h) over 256 entries: wave shfl scan
    unsigned pv = 0, px = 0;
    if (tid < MAXNB) {
        pv = roundup16(h[tid]);
        px = pv;
#pragma unroll
        for (int off = 1; off < 64; off <<= 1) {
            unsigned t = __shfl_up(px, off, 64);
            if ((tid & 63) >= off) px += t;
        }
        if ((tid & 63) == 63) wsum[tid >> 6] = px;
    }
    __syncthreads();
    if (tid < 8) {
        unsigned acc = 0;
        for (int k = 0; k < tid; ++k) acc += wsum[k];
        wbase[tid] = acc;
    }
    __syncthreads();
    if (tid < MAXNB) {
        unsigned ex = px - pv + wbase[tid >> 6];
        lbase[tid] = ex;
        if (tid < nb && h[tid])
            bs_[tid] = (unsigned)(tid * CAP) + atomicAdd(&bfill[tid * BPAD], roundup16(h[tid]));
    }
    __syncthreads();
    // scatter from registers into LDS (bucket-sorted)
#pragma unroll
    for (int j = 0; j < 16; ++j) {
        int idx = j * 512 + tid;
        if (idx < cn) {
            unsigned b = bkt[j];
            unsigned pos = lbase[b] + atomicAdd(&cur[b], 1u);
            sorted[pos] = key[j];
        }
    }
    // sentinel-fill ONLY the pad slots
    for (int b = tid; b < nb; b += 512) {
        unsigned hb = h[b];
        if (!hb) continue;
        unsigned k0 = lbase[b] + hb;
        unsigned k1 = lbase[b] + roundup16(hb);
        for (unsigned k = k0; k < k1; ++k) sorted[k] = SENT;
    }
    __syncthreads();
    // burst copy: 8-lane group per bucket (64 groups), uint4 contiguous stores
    int grp = tid >> 3;
    int ln8 = tid & 7;
    for (int b = grp; b < nb; b += 64) {
        unsigned np = roundup16(h[b]) >> 2;   // uint4 count
        if (!np) continue;
        const uint4* sp = reinterpret_cast<const uint4*>(&sorted[lbase[b]]);
        uint4* gp = reinterpret_cast<uint4*>(&pairs[bs_[b]]);
        for (unsigned k = ln8; k < np; k += 8) gp[k] = sp[k];
    }
}

// per-bucket (1024 threads), SINGLE global pass: register-stash pairs ->
// hist -> wave scan over roundup8(deg) -> cnt/dis/rstart/xd + dummy pads ->
// scatter from registers into 96KB LDS srt -> coalesced uint4 burst -> esrc.
__global__ __launch_bounds__(1024) void k_binB(const unsigned* __restrict__ pairs,
                                               const unsigned* __restrict__ bfill,
                                               const float* __restrict__ x,
                                               int* __restrict__ cnt, float* __restrict__ dis,
                                               int* __restrict__ rstart, int* __restrict__ esrc,
                                               unsigned* __restrict__ xd, int N) {
    __shared__ unsigned h[NPB];
    __shared__ unsigned cur[NPB];    // scatter cursor (starts at padded excl scan)
    __shared__ unsigned wsum[8];
    __shared__ unsigned wbase[8];
    __shared__ unsigned tot_s;
    __shared__ __attribute__((aligned(16))) unsigned srt[CAP];   // 96KB node-sorted
    int tid = threadIdx.x, b = blockIdx.x;
    if (tid < NPB) h[tid] = 0;
    __syncthreads();
    int r0 = b * CAP;
    int n4 = (int)bfill[b * BPAD] >> 2;
    const uint4* p4 = reinterpret_cast<const uint4*>(pairs + r0);
    uint4 rs[6];                     // 6*1024 = 6144 uint4 = CAP exactly
#pragma unroll
    for (int k = 0; k < 6; ++k) {
        int idx = k * 1024 + tid;
        if (idx < n4) {
            rs[k] = p4[idx];
            uint4 p = rs[k];
            if (p.x != SENT) atomicAdd(&h[p.x & BMSK], 1u);
            if (p.y != SENT) atomicAdd(&h[p.y & BMSK], 1u);
            if (p.z != SENT) atomicAdd(&h[p.z & BMSK], 1u);
            if (p.w != SENT) atomicAdd(&h[p.w & BMSK], 1u);
        }
    }
    __syncthreads();
    // exclusive scan over roundup8(counts) (first 512 threads): wave shfl scan
    unsigned v = 0, pv = 0, x2 = 0;
    if (tid < NPB) {
        v = h[tid];
        pv = roundup8(v);
        x2 = pv;
#pragma unroll
        for (int off = 1; off < 64; off <<= 1) {
            unsigned t = __shfl_up(x2, off, 64);
            if ((tid & 63) >= off) x2 += t;
        }
        if ((tid & 63) == 63) wsum[tid >> 6] = x2;
    }
    __syncthreads();
    if (tid < 8) {
        unsigned acc = 0;
        for (int k = 0; k < tid; ++k) acc += wsum[k];
        wbase[tid] = acc;
    }
    __syncthreads();
    if (tid < NPB) {
        unsigned ex = x2 - pv + wbase[tid >> 6];
        cur[tid] = ex;               // real edges fill [ex, ex+v)
        if (tid == NPB - 1) tot_s = ex + pv;
        // dummy pad fill [ex+v, ex+pv): index N -> zero row
        for (unsigned k = ex + v; k < ex + pv; ++k) srt[k] = (unsigned)N;
        int node = (b << BSH) + tid;
        if (node < N) {
            float d = rsqrtf((float)(v + 1u));   // real degree for norm
            cnt[node] = (int)pv;                 // padded count for gather loops
            dis[node] = d;
            rstart[node] = r0 + (int)ex;
            const float4* xp = reinterpret_cast<const float4*>(x + (size_t)node * F0);
            unsigned pk[8];
#pragma unroll
            for (int q = 0; q < 4; ++q) {
                float4 vv = xp[q];
                pk[2 * q + 0] = f2bf(d * vv.x) | (f2bf(d * vv.y) << 16);
                pk[2 * q + 1] = f2bf(d * vv.z) | (f2bf(d * vv.w) << 16);
            }
            uint4* o = reinterpret_cast<uint4*>(xd + (size_t)node * 8);
            o[0] = make_uint4(pk[0], pk[1], pk[2], pk[3]);
            o[1] = make_uint4(pk[4], pk[5], pk[6], pk[7]);
        }
    }
    __syncthreads();
    // scatter from REGISTERS into LDS srt (no second global pass)
#pragma unroll
    for (int k = 0; k < 6; ++k) {
        int idx = k * 1024 + tid;
        if (idx < n4) {
            uint4 p = rs[k];
            if (p.x != SENT) { unsigned o_ = atomicAdd(&cur[p.x & BMSK], 1u); srt[o_] = p.x >> BSH; }
            if (p.y != SENT) { unsigned o_ = atomicAdd(&cur[p.y & BMSK], 1u); srt[o_] = p.y >> BSH; }
            if (p.z != SENT) { unsigned o_ = atomicAdd(&cur[p.z & BMSK], 1u); srt[o_] = p.z >> BSH; }
            if (p.w != SENT) { unsigned o_ = atomicAdd(&cur[p.w & BMSK], 1u); srt[o_] = p.w >> BSH; }
        }
    }
    __syncthreads();
    // coalesced burst copy srt -> esrc (uint4; tot_s is multiple of 8)
    unsigned tot4 = tot_s >> 2;
    const uint4* s4 = reinterpret_cast<const uint4*>(srt);
    uint4* g4 = reinterpret_cast<uint4*>(esrc + r0);
    for (unsigned k = tid; k < tot4; k += 1024) g4[k] = s4[k];
}

// fused layer1: 8 lanes/node gather-aggregate xd (1 u32/lane = 32B/row),
// 32/16/8-edge chunks (int4/int2 esrc loads, up to 32 gathers in flight),
// then in-register MLP. Edge lists padded to x8 -> no serial tail.
__global__ void k_layer1(const unsigned* __restrict__ xd, const int* __restrict__ cnt,
                         const int* __restrict__ rstart, const int* __restrict__ esrc,
                         const float* __restrict__ dis, const float* __restrict__ b1,
                         const float* __restrict__ W1, const float* __restrict__ W2,
                         float* __restrict__ g2, int N) {
    __shared__ float w1[F0 * F1];
    __shared__ float w2[F1 * F2];
    __shared__ float bb[F1];
    __shared__ float ymat[32][17];   // 32 nodes/block, +1 pad
    for (int j = threadIdx.x; j < F0 * F1; j += blockDim.x) w1[j] = W1[j];
    for (int j = threadIdx.x; j < F1 * F2; j += blockDim.x) w2[j] = W2[j];
    for (int j = threadIdx.x; j < F1; j += blockDim.x) bb[j] = b1[j];
    __syncthreads();
    int t = blockIdx.x * blockDim.x + threadIdx.x;
    int v = t >> 3;
    int q = t & 7;
    if (v >= N) return;
    const unsigned* base = xd + q;             // row stride 8 u32
    unsigned sw = base[(size_t)v * 8];         // self loop xd[v]
    float a0 = bf2f(sw & 0xffffu);
    float a1 = bf2f(sw >> 16);
    int beg = rstart[v];
    int n = cnt[v];                            // multiple of 8
    int j = 0;
    for (; j + 32 <= n; j += 32) {             // 32 edges: int4 esrc per lane
        int4 iv = *reinterpret_cast<const int4*>(&esrc[beg + j + 4 * q]);
#pragma unroll
        for (int u = 0; u < 8; ++u) {
            int s0 = __shfl(iv.x, u, 8);
            int s1 = __shfl(iv.y, u, 8);
            int s2 = __shfl(iv.z, u, 8);
            int s3 = __shfl(iv.w, u, 8);
            unsigned a = base[(size_t)s0 * 8];
            unsigned c = base[(size_t)s1 * 8];
            unsigned e = base[(size_t)s2 * 8];
            unsigned f = base[(size_t)s3 * 8];
            a0 += bf2f(a & 0xffffu) + bf2f(c & 0xffffu) + bf2f(e & 0xffffu) + bf2f(f & 0xffffu);
            a1 += bf2f(a >> 16) + bf2f(c >> 16) + bf2f(e >> 16) + bf2f(f >> 16);
        }
    }
    if (j + 16 <= n) {                         // 16 edges: int2 esrc per lane
        int2 iv = *reinterpret_cast<const int2*>(&esrc[beg + j + 2 * q]);
#pragma unroll
        for (int u = 0; u < 8; ++u) {
            int s0 = __shfl(iv.x, u, 8);
            int s1 = __shfl(iv.y, u, 8);
            unsigned a = base[(size_t)s0 * 8];
            unsigned c = base[(size_t)s1 * 8];
            a0 += bf2f(a & 0xffffu) + bf2f(c & 0xffffu);
            a1 += bf2f(a >> 16) + bf2f(c >> 16);
        }
        j += 16;
    }
    if (j < n) {                               // exactly one 8-edge chunk
        int idx = esrc[beg + j + q];
#pragma unroll
        for (int u = 0; u < 8; ++u) {
            int s = __shfl(idx, u, 8);
            unsigned a = base[(size_t)s * 8];
            a0 += bf2f(a & 0xffffu);
            a1 += bf2f(a >> 16);
        }
    }
    // exchange y within the 8-lane group (wave-local LDS, lockstep)
    int ln = threadIdx.x >> 3;
    ymat[ln][2 * q + 0] = a0;
    ymat[ln][2 * q + 1] = a1;
    float y[F0];
#pragma unroll
    for (int k = 0; k < F0; ++k) y[k] = ymat[ln][k];
    float d = dis[v];
    float p0 = 0.0f, p1 = 0.0f;
#pragma unroll
    for (int u = 0; u < 4; ++u) {
        int jf = q * 4 + u;                    // 32 features across 8 lanes x 4
        float s = 0.0f;
#pragma unroll
        for (int k = 0; k < F0; ++k) s = fmaf(y[k], w1[k * F1 + jf], s);
        float r = fmaxf(fmaf(d, s, bb[jf]), 0.0f);
        p0 = fmaf(r, w2[jf * F2 + 0], p0);
        p1 = fmaf(r, w2[jf * F2 + 1], p1);
    }
#pragma unroll
    for (int off = 1; off < 8; off <<= 1) {
        p0 += __shfl_xor(p0, off);
        p1 += __shfl_xor(p1, off);
    }
    if (q == 0) {
        g2[(size_t)v * F2 + 0] = d * p0;
        g2[(size_t)v * F2 + 1] = d * p1;
    }
}

// fused layer2 aggregate + output: 4 lanes per node, 8 gathers in flight
__global__ void k_out2(const float* __restrict__ g2, const int* __restrict__ cnt,
                       const int* __restrict__ rstart, const int* __restrict__ esrc,
                       const float* __restrict__ dis, const float* __restrict__ b2,
                       float* __restrict__ out, int N) {
    int t = blockIdx.x * blockDim.x + threadIdx.x;
    int v = t >> 2;
    int l = t & 3;
    if (v >= N) return;
    float o0 = 0.0f, o1 = 0.0f;
    int beg = rstart[v];
    int end = beg + cnt[v];              // padded; dummies gather g2[N]=0
    int j = beg + l;
    for (; j + 28 < end; j += 32) {      // 8 independent gathers in flight
        int s0 = esrc[j];
        int s1 = esrc[j + 4];
        int s2 = esrc[j + 8];
        int s3 = esrc[j + 12];
        int s4 = esrc[j + 16];
        int s5 = esrc[j + 20];
        int s6 = esrc[j + 24];
        int s7 = esrc[j + 28];
        float2 a0 = *reinterpret_cast<const float2*>(g2 + (size_t)s0 * F2);
        float2 a1 = *reinterpret_cast<const float2*>(g2 + (size_t)s1 * F2);
        float2 a2 = *reinterpret_cast<const float2*>(g2 + (size_t)s2 * F2);
        float2 a3 = *reinterpret_cast<const float2*>(g2 + (size_t)s3 * F2);
        float2 a4 = *reinterpret_cast<const float2*>(g2 + (size_t)s4 * F2);
        float2 a5 = *reinterpret_cast<const float2*>(g2 + (size_t)s5 * F2);
        float2 a6 = *reinterpret_cast<const float2*>(g2 + (size_t)s6 * F2);
        float2 a7 = *reinterpret_cast<const float2*>(g2 + (size_t)s7 * F2);
        o0 += a0.x + a1.x + a2.x + a3.x + a4.x + a5.x + a6.x + a7.x;
        o1 += a0.y + a1.y + a2.y + a3.y + a4.y + a5.y + a6.y + a7.y;
    }
    for (; j + 12 < end; j += 16) {      // 4 in flight
        int s0 = esrc[j];
        int s1 = esrc[j + 4];
        int s2 = esrc[j + 8];
        int s3 = esrc[j + 12];
        float2 a0 = *reinterpret_cast<const float2*>(g2 + (size_t)s0 * F2);
        float2 a1 = *reinterpret_cast<const float2*>(g2 + (size_t)s1 * F2);
        float2 a2 = *reinterpret_cast<const float2*>(g2 + (size_t)s2 * F2);
        float2 a3 = *reinterpret_cast<const float2*>(g2 + (size_t)s3 * F2);
        o0 += a0.x + a1.x + a2.x + a3.x;
        o1 += a0.y + a1.y + a2.y + a3.y;
    }
    for (; j < end; j += 4) {
        int s = esrc[j];
        const float2 a = *reinterpret_cast<const float2*>(g2 + (size_t)s * F2);
        o0 += a.x; o1 += a.y;
    }
#pragma unroll
    for (int off = 1; off < 4; off <<= 1) {
        o0 += __shfl_xor(o0, off);
        o1 += __shfl_xor(o1, off);
    }
    if (l == 0) {
        float d = dis[v];
        const float2 self = *reinterpret_cast<const float2*>(g2 + (size_t)v * F2);
        out[(size_t)v * F2 + 0] = fmaf(d, o0 + self.x, b2[0]);
        out[(size_t)v * F2 + 1] = fmaf(d, o1 + self.y, b2[1]);
    }
}

extern "C" void kernel_launch(void* const* d_in, const int* in_sizes, int n_in,
                              void* d_out, int out_size, void* d_ws, size_t ws_size,
                              hipStream_t stream) {
    const float* x  = (const float*)d_in[0];
    const int* ei   = (const int*)d_in[1];
    const float* W1 = (const float*)d_in[2];
    const float* b1 = (const float*)d_in[3];
    const float* W2 = (const float*)d_in[4];
    const float* b2 = (const float*)d_in[5];
    float* out = (float*)d_out;

    const int N = in_sizes[0] / F0;          // 100000
    const int E = in_sizes[1] / 2;           // 3200000
    const int* src = ei;
    const int* dst = ei + E;
    const int nb = (N + BMSK) >> BSH;        // 196 buckets of 512 nodes
    const int nchunk = (E + EPB - 1) / EPB;  // 391 chunks

    // workspace layout (u32 units); pairs 16B-aligned
    unsigned* bfill = (unsigned*)d_ws;                    // MAXNB*BPAD (16KB)
    unsigned* pairs = bfill + MAXNB * BPAD;               // nb*CAP (~19.3MB)
    int* esrc       = (int*)(pairs + (size_t)nb * CAP);   // nb*CAP (~19.3MB)
    unsigned* xd    = (unsigned*)(esrc + (size_t)nb * CAP); // 8*(N+1) (32B rows + dummy)
    float* dis      = (float*)(xd + (size_t)8 * (N + 1)); // N
    int* cnt        = (int*)(dis + N);                    // N
    int* rstart     = cnt + N;                            // N
    float* g2       = (float*)(rstart + N);               // 2*(N+1)
    // total ~ 44 MB

    const int B = 256;
    const int nz = MAXNB * BPAD;
    k_zero<<<(nz + B - 1) / B, B, 0, stream>>>(bfill, nz,
                                               xd + (size_t)8 * N,
                                               (unsigned*)(g2 + (size_t)2 * N));
    k_binA<<<nchunk, 512, 0, stream>>>(src, dst, bfill, pairs, E, nb);
    k_binB<<<nb, 1024, 0, stream>>>(pairs, bfill, x, cnt, dis, rstart, esrc, xd, N);
    k_layer1<<<(N * 8 + B - 1) / B, B, 0, stream>>>(xd, cnt, rstart, esrc, dis, b1, W1, W2, g2, N);
    k_out2<<<(N * 4 + B - 1) / B, B, 0, stream>>>(g2, cnt, rstart, esrc, dis, b2, out, N);
}

// Round 24
// 82.640 us; speedup vs baseline: 1.1283x; 1.0331x over previous
//
#include <hip/hip_runtime.h>

// GCN 2-layer, 5 dispatches:
//   zero: clear bfill (16KB) + dummy rows xd[N], g2[N]
//   binA: chunk-wise LDS counting sort of edges by dst-bucket (512 nodes),
//         BLOCKED int4 edge loads (8 vector loads/thread vs 32 scalar),
//         register-stashed, 64B-aligned reservations into FIXED per-bucket
//         regions (b*CAP). 8-lane-group burst copy.
//   binB: one block per bucket, 1024 threads, SINGLE pass over pairs:
//         region register-stashed (6 uint4/thread) -> hist -> wave scan over
//         roundup8(deg) -> cnt(padded)/dis/rstart/xd + dummy pad fill ->
//         scatter from registers into 96KB LDS srt -> uint4 burst -> esrc.
//   layer1: per-node 8-lane gather-aggregate of xd rows (32B, L2-resident),
//         32/16/8-edge chunks (int4/int2 esrc loads), in-register MLP -> g2
//   out2: per-node 4-lane gather-aggregate of g2, contiguous int4/int2 esrc
//         segments per lane (16 gathers in flight) -> out
// norm trick: g = dis*(h@W); out[v] = dis[v]*(sum_{u->v} g[u] + g[v]) + b.

static constexpr int F0 = 16;
static constexpr int F1 = 32;
static constexpr int F2 = 2;
static constexpr int BSH  = 9;      // bucket = dst>>9 (512 nodes)
static constexpr int BMSK = 511;
static constexpr int NPB  = 512;    // nodes per bucket
static constexpr int MAXNB = 256;   // max coarse buckets (scan width)
static constexpr int NBMAX = 196;   // actual bucket count for N=100000
static constexpr int BPAD  = 16;    // cursor padded to own 64B line
static constexpr int EPB   = 8192;  // edges per binA chunk (= 16 per thread)
static constexpr int CAP   = 24576; // slots per bucket region (= 6144 uint4)
static constexpr int SORTCAP = EPB + NBMAX * 16;   // 11328 (~45KB)
static constexpr unsigned SENT = 0xFFFFFFFFu;

__device__ inline unsigned roundup16(unsigned h) { return (h + 15u) & ~15u; }
__device__ inline unsigned roundup8(unsigned h)  { return (h + 7u) & ~7u; }

__device__ inline unsigned f2bf(float f) {
    unsigned u = __float_as_uint(f);
    return (u + 0x7fffu + ((u >> 16) & 1u)) >> 16;   // RNE
}
__device__ inline float bf2f(unsigned b) {
    return __uint_as_float(b << 16);
}

// grid-stride zero + dummy-row clear (xd row N: 8 words; g2 row N: 2 words)
__global__ void k_zero(unsigned* __restrict__ p, int n,
                       unsigned* __restrict__ xdN, unsigned* __restrict__ g2N) {
    int i = blockIdx.x * blockDim.x + threadIdx.x;
    if (i < n) p[i] = 0u;
    if (i < 8) xdN[i] = 0u;
    if (i < 2) g2N[i] = 0u;
}

// LDS counting sort of a chunk (blocked int4 edge loads into registers),
// then per-bucket 8-lane-group burst copy to global.
__global__ __launch_bounds__(512) void k_binA(const int* __restrict__ src,
                                              const int* __restrict__ dst,
                                              unsigned* __restrict__ bfill,
                                              unsigned* __restrict__ pairs,
                                              int E, int nb) {
    __shared__ unsigned h[MAXNB];
    __shared__ unsigned lbase[MAXNB];
    __shared__ unsigned bs_[MAXNB];
    __shared__ unsigned cur[MAXNB];
    __shared__ unsigned wsum[8];
    __shared__ unsigned wbase[8];
    __shared__ __attribute__((aligned(16))) unsigned sorted[SORTCAP];
    int tid = threadIdx.x;
    for (int b = tid; b < MAXNB; b += 512) { h[b] = 0; cur[b] = 0; }
    if (tid < 8) wsum[tid] = 0;
    __syncthreads();
    int e0 = blockIdx.x * EPB;
    int cn = min(EPB, E - e0);
    int base16 = 16 * tid;                 // blocked: this thread's 16 edges
    int nv = cn - base16;                  // valid count (<=0 none, >=16 all)
    nv = nv < 0 ? 0 : (nv > 16 ? 16 : nv);
    unsigned key[16];
    unsigned bkt[16];
    if (nv == 16) {                        // fast path: 4x int4 dst + src
        const int4* dp = reinterpret_cast<const int4*>(dst + e0 + base16);
        const int4* sp = reinterpret_cast<const int4*>(src + e0 + base16);
#pragma unroll
        for (int k = 0; k < 4; ++k) {
            int4 dv = dp[k];
            int4 sv = sp[k];
            int dd[4] = { dv.x, dv.y, dv.z, dv.w };
            int ss[4] = { sv.x, sv.y, sv.z, sv.w };
#pragma unroll
            for (int u = 0; u < 4; ++u) {
                unsigned d = (unsigned)dd[u];
                unsigned b = d >> BSH;
                key[4 * k + u] = (((unsigned)ss[u]) << BSH) | (d & BMSK);
                bkt[4 * k + u] = b;
                atomicAdd(&h[b], 1u);
            }
        }
    } else {                               // tail path: scalar with guard
#pragma unroll
        for (int j = 0; j < 16; ++j) {
            if (j < nv) {
                unsigned d = (unsigned)dst[e0 + base16 + j];
                unsigned s = (unsigned)src[e0 + base16 + j];
                unsigned b = d >> BSH;
                key[j] = (s << BSH) | (d & BMSK);
                bkt[j] = b;
                atomicAdd(&h[b], 1u);
            }
        }
    }
    __syncthreads();
    // exclusive scan of roundup16(h) over 256 entries: wave shfl scan
    unsigned pv = 0, px = 0;
    if (tid < MAXNB) {
        pv = roundup16(h[tid]);
        px = pv;
#pragma unroll
        for (int off = 1; off < 64; off <<= 1) {
            unsigned t = __shfl_up(px, off, 64);
            if ((tid & 63) >= off) px += t;
        }
        if ((tid & 63) == 63) wsum[tid >> 6] = px;
    }
    __syncthreads();
    if (tid < 8) {
        unsigned acc = 0;
        for (int k = 0; k < tid; ++k) acc += wsum[k];
        wbase[tid] = acc;
    }
    __syncthreads();
    if (tid < MAXNB) {
        unsigned ex = px - pv + wbase[tid >> 6];
        lbase[tid] = ex;
        if (tid < nb && h[tid])
            bs_[tid] = (unsigned)(tid * CAP) + atomicAdd(&bfill[tid * BPAD], roundup16(h[tid]));
    }
    __syncthreads();
    // scatter from registers into LDS (bucket-sorted)
#pragma unroll
    for (int j = 0; j < 16; ++j) {
        if (j < nv) {
            unsigned b = bkt[j];
            unsigned pos = lbase[b] + atomicAdd(&cur[b], 1u);
            sorted[pos] = key[j];
        }
    }
    // sentinel-fill ONLY the pad slots
    for (int b = tid; b < nb; b += 512) {
        unsigned hb = h[b];
        if (!hb) continue;
        unsigned k0 = lbase[b] + hb;
        unsigned k1 = lbase[b] + roundup16(hb);
        for (unsigned k = k0; k < k1; ++k) sorted[k] = SENT;
    }
    __syncthreads();
    // burst copy: 8-lane group per bucket (64 groups), uint4 contiguous stores
    int grp = tid >> 3;
    int ln8 = tid & 7;
    for (int b = grp; b < nb; b += 64) {
        unsigned np = roundup16(h[b]) >> 2;   // uint4 count
        if (!np) continue;
        const uint4* sp = reinterpret_cast<const uint4*>(&sorted[lbase[b]]);
        uint4* gp = reinterpret_cast<uint4*>(&pairs[bs_[b]]);
        for (unsigned k = ln8; k < np; k += 8) gp[k] = sp[k];
    }
}

// per-bucket (1024 threads), SINGLE global pass: register-stash pairs ->
// hist -> wave scan over roundup8(deg) -> cnt/dis/rstart/xd + dummy pads ->
// scatter from registers into 96KB LDS srt -> coalesced uint4 burst -> esrc.
__global__ __launch_bounds__(1024) void k_binB(const unsigned* __restrict__ pairs,
                                               const unsigned* __restrict__ bfill,
                                               const float* __restrict__ x,
                                               int* __restrict__ cnt, float* __restrict__ dis,
                                               int* __restrict__ rstart, int* __restrict__ esrc,
                                               unsigned* __restrict__ xd, int N) {
    __shared__ unsigned h[NPB];
    __shared__ unsigned cur[NPB];    // scatter cursor (starts at padded excl scan)
    __shared__ unsigned wsum[8];
    __shared__ unsigned wbase[8];
    __shared__ unsigned tot_s;
    __shared__ __attribute__((aligned(16))) unsigned srt[CAP];   // 96KB node-sorted
    int tid = threadIdx.x, b = blockIdx.x;
    if (tid < NPB) h[tid] = 0;
    __syncthreads();
    int r0 = b * CAP;
    int n4 = (int)bfill[b * BPAD] >> 2;
    const uint4* p4 = reinterpret_cast<const uint4*>(pairs + r0);
    uint4 rs[6];                     // 6*1024 = 6144 uint4 = CAP exactly
#pragma unroll
    for (int k = 0; k < 6; ++k) {
        int idx = k * 1024 + tid;
        if (idx < n4) {
            rs[k] = p4[idx];
            uint4 p = rs[k];
            if (p.x != SENT) atomicAdd(&h[p.x & BMSK], 1u);
            if (p.y != SENT) atomicAdd(&h[p.y & BMSK], 1u);
            if (p.z != SENT) atomicAdd(&h[p.z & BMSK], 1u);
            if (p.w != SENT) atomicAdd(&h[p.w & BMSK], 1u);
        }
    }
    __syncthreads();
    // exclusive scan over roundup8(counts) (first 512 threads): wave shfl scan
    unsigned v = 0, pv = 0, x2 = 0;
    if (tid < NPB) {
        v = h[tid];
        pv = roundup8(v);
        x2 = pv;
#pragma unroll
        for (int off = 1; off < 64; off <<= 1) {
            unsigned t = __shfl_up(x2, off, 64);
            if ((tid & 63) >= off) x2 += t;
        }
        if ((tid & 63) == 63) wsum[tid >> 6] = x2;
    }
    __syncthreads();
    if (tid < 8) {
        unsigned acc = 0;
        for (int k = 0; k < tid; ++k) acc += wsum[k];
        wbase[tid] = acc;
    }
    __syncthreads();
    if (tid < NPB) {
        unsigned ex = x2 - pv + wbase[tid >> 6];
        cur[tid] = ex;               // real edges fill [ex, ex+v)
        if (tid == NPB - 1) tot_s = ex + pv;
        // dummy pad fill [ex+v, ex+pv): index N -> zero row
        for (unsigned k = ex + v; k < ex + pv; ++k) srt[k] = (unsigned)N;
        int node = (b << BSH) + tid;
        if (node < N) {
            float d = rsqrtf((float)(v + 1u));   // real degree for norm
            cnt[node] = (int)pv;                 // padded count for gather loops
            dis[node] = d;
            rstart[node] = r0 + (int)ex;
            const float4* xp = reinterpret_cast<const float4*>(x + (size_t)node * F0);
            unsigned pk[8];
#pragma unroll
            for (int q = 0; q < 4; ++q) {
                float4 vv = xp[q];
                pk[2 * q + 0] = f2bf(d * vv.x) | (f2bf(d * vv.y) << 16);
                pk[2 * q + 1] = f2bf(d * vv.z) | (f2bf(d * vv.w) << 16);
            }
            uint4* o = reinterpret_cast<uint4*>(xd + (size_t)node * 8);
            o[0] = make_uint4(pk[0], pk[1], pk[2], pk[3]);
            o[1] = make_uint4(pk[4], pk[5], pk[6], pk[7]);
        }
    }
    __syncthreads();
    // scatter from REGISTERS into LDS srt (no second global pass)
#pragma unroll
    for (int k = 0; k < 6; ++k) {
        int idx = k * 1024 + tid;
        if (idx < n4) {
            uint4 p = rs[k];
            if (p.x != SENT) { unsigned o_ = atomicAdd(&cur[p.x & BMSK], 1u); srt[o_] = p.x >> BSH; }
            if (p.y != SENT) { unsigned o_ = atomicAdd(&cur[p.y & BMSK], 1u); srt[o_] = p.y >> BSH; }
            if (p.z != SENT) { unsigned o_ = atomicAdd(&cur[p.z & BMSK], 1u); srt[o_] = p.z >> BSH; }
            if (p.w != SENT) { unsigned o_ = atomicAdd(&cur[p.w & BMSK], 1u); srt[o_] = p.w >> BSH; }
        }
    }
    __syncthreads();
    // coalesced burst copy srt -> esrc (uint4; tot_s is multiple of 8)
    unsigned tot4 = tot_s >> 2;
    const uint4* s4 = reinterpret_cast<const uint4*>(srt);
    uint4* g4 = reinterpret_cast<uint4*>(esrc + r0);
    for (unsigned k = tid; k < tot4; k += 1024) g4[k] = s4[k];
}

// fused layer1: 8 lanes/node gather-aggregate xd (1 u32/lane = 32B/row),
// 32/16/8-edge chunks (int4/int2 esrc loads, up to 32 gathers in flight),
// then in-register MLP. Edge lists padded to x8 -> no serial tail.
__global__ void k_layer1(const unsigned* __restrict__ xd, const int* __restrict__ cnt,
                         const int* __restrict__ rstart, const int* __restrict__ esrc,
                         const float* __restrict__ dis, const float* __restrict__ b1,
                         const float* __restrict__ W1, const float* __restrict__ W2,
                         float* __restrict__ g2, int N) {
    __shared__ float w1[F0 * F1];
    __shared__ float w2[F1 * F2];
    __shared__ float bb[F1];
    __shared__ float ymat[32][17];   // 32 nodes/block, +1 pad
    for (int j = threadIdx.x; j < F0 * F1; j += blockDim.x) w1[j] = W1[j];
    for (int j = threadIdx.x; j < F1 * F2; j += blockDim.x) w2[j] = W2[j];
    for (int j = threadIdx.x; j < F1; j += blockDim.x) bb[j] = b1[j];
    __syncthreads();
    int t = blockIdx.x * blockDim.x + threadIdx.x;
    int v = t >> 3;
    int q = t & 7;
    if (v >= N) return;
    const unsigned* base = xd + q;             // row stride 8 u32
    unsigned sw = base[(size_t)v * 8];         // self loop xd[v]
    float a0 = bf2f(sw & 0xffffu);
    float a1 = bf2f(sw >> 16);
    int beg = rstart[v];
    int n = cnt[v];                            // multiple of 8
    int j = 0;
    for (; j + 32 <= n; j += 32) {             // 32 edges: int4 esrc per lane
        int4 iv = *reinterpret_cast<const int4*>(&esrc[beg + j + 4 * q]);
#pragma unroll
        for (int u = 0; u < 8; ++u) {
            int s0 = __shfl(iv.x, u, 8);
            int s1 = __shfl(iv.y, u, 8);
            int s2 = __shfl(iv.z, u, 8);
            int s3 = __shfl(iv.w, u, 8);
            unsigned a = base[(size_t)s0 * 8];
            unsigned c = base[(size_t)s1 * 8];
            unsigned e = base[(size_t)s2 * 8];
            unsigned f = base[(size_t)s3 * 8];
            a0 += bf2f(a & 0xffffu) + bf2f(c & 0xffffu) + bf2f(e & 0xffffu) + bf2f(f & 0xffffu);
            a1 += bf2f(a >> 16) + bf2f(c >> 16) + bf2f(e >> 16) + bf2f(f >> 16);
        }
    }
    if (j + 16 <= n) {                         // 16 edges: int2 esrc per lane
        int2 iv = *reinterpret_cast<const int2*>(&esrc[beg + j + 2 * q]);
#pragma unroll
        for (int u = 0; u < 8; ++u) {
            int s0 = __shfl(iv.x, u, 8);
            int s1 = __shfl(iv.y, u, 8);
            unsigned a = base[(size_t)s0 * 8];
            unsigned c = base[(size_t)s1 * 8];
            a0 += bf2f(a & 0xffffu) + bf2f(c & 0xffffu);
            a1 += bf2f(a >> 16) + bf2f(c >> 16);
        }
        j += 16;
    }
    if (j < n) {                               // exactly one 8-edge chunk
        int idx = esrc[beg + j + q];
#pragma unroll
        for (int u = 0; u < 8; ++u) {
            int s = __shfl(idx, u, 8);
            unsigned a = base[(size_t)s * 8];
            a0 += bf2f(a & 0xffffu);
            a1 += bf2f(a >> 16);
        }
    }
    // exchange y within the 8-lane group (wave-local LDS, lockstep)
    int ln = threadIdx.x >> 3;
    ymat[ln][2 * q + 0] = a0;
    ymat[ln][2 * q + 1] = a1;
    float y[F0];
#pragma unroll
    for (int k = 0; k < F0; ++k) y[k] = ymat[ln][k];
    float d = dis[v];
    float p0 = 0.0f, p1 = 0.0f;
#pragma unroll
    for (int u = 0; u < 4; ++u) {
        int jf = q * 4 + u;                    // 32 features across 8 lanes x 4
        float s = 0.0f;
#pragma unroll
        for (int k = 0; k < F0; ++k) s = fmaf(y[k], w1[k * F1 + jf], s);
        float r = fmaxf(fmaf(d, s, bb[jf]), 0.0f);
        p0 = fmaf(r, w2[jf * F2 + 0], p0);
        p1 = fmaf(r, w2[jf * F2 + 1], p1);
    }
#pragma unroll
    for (int off = 1; off < 8; off <<= 1) {
        p0 += __shfl_xor(p0, off);
        p1 += __shfl_xor(p1, off);
    }
    if (q == 0) {
        g2[(size_t)v * F2 + 0] = d * p0;
        g2[(size_t)v * F2 + 1] = d * p1;
    }
}

// fused layer2 aggregate + output: 4 lanes/node, contiguous int4/int2 esrc
// segments per lane -> 16 independent g2 gathers in flight per group.
__global__ void k_out2(const float* __restrict__ g2, const int* __restrict__ cnt,
                       const int* __restrict__ rstart, const int* __restrict__ esrc,
                       const float* __restrict__ dis, const float* __restrict__ b2,
                       float* __restrict__ out, int N) {
    int t = blockIdx.x * blockDim.x + threadIdx.x;
    int v = t >> 2;
    int l = t & 3;
    if (v >= N) return;
    float o0 = 0.0f, o1 = 0.0f;
    int beg = rstart[v];
    int n = cnt[v];                      // multiple of 8; dummies gather g2[N]=0
    int j = 0;
    for (; j + 16 <= n; j += 16) {       // lane l owns edges [j+4l, j+4l+3]
        int4 iv = *reinterpret_cast<const int4*>(&esrc[beg + j + 4 * l]);
        float2 a0 = *reinterpret_cast<const float2*>(g2 + (size_t)iv.x * F2);
        float2 a1 = *reinterpret_cast<const float2*>(g2 + (size_t)iv.y * F2);
        float2 a2 = *reinterpret_cast<const float2*>(g2 + (size_t)iv.z * F2);
        float2 a3 = *reinterpret_cast<const float2*>(g2 + (size_t)iv.w * F2);
        o0 += a0.x + a1.x + a2.x + a3.x;
        o1 += a0.y + a1.y + a2.y + a3.y;
    }
    if (j < n) {                         // one 8-edge chunk: int2 per lane
        int2 iv = *reinterpret_cast<const int2*>(&esrc[beg + j + 2 * l]);
        float2 a0 = *reinterpret_cast<const float2*>(g2 + (size_t)iv.x * F2);
        float2 a1 = *reinterpret_cast<const float2*>(g2 + (size_t)iv.y * F2);
        o0 += a0.x + a1.x;
        o1 += a0.y + a1.y;
    }
#pragma unroll
    for (int off = 1; off < 4; off <<= 1) {
        o0 += __shfl_xor(o0, off);
        o1 += __shfl_xor(o1, off);
    }
    if (l == 0) {
        float d = dis[v];
        const float2 self = *reinterpret_cast<const float2*>(g2 + (size_t)v * F2);
        out[(size_t)v * F2 + 0] = fmaf(d, o0 + self.x, b2[0]);
        out[(size_t)v * F2 + 1] = fmaf(d, o1 + self.y, b2[1]);
    }
}

extern "C" void kernel_launch(void* const* d_in, const int* in_sizes, int n_in,
                              void* d_out, int out_size, void* d_ws, size_t ws_size,
                              hipStream_t stream) {
    const float* x  = (const float*)d_in[0];
    const int* ei   = (const int*)d_in[1];
    const float* W1 = (const float*)d_in[2];
    const float* b1 = (const float*)d_in[3];
    const float* W2 = (const float*)d_in[4];
    const float* b2 = (const float*)d_in[5];
    float* out = (float*)d_out;

    const int N = in_sizes[0] / F0;          // 100000
    const int E = in_sizes[1] / 2;           // 3200000
    const int* src = ei;
    const int* dst = ei + E;
    const int nb = (N + BMSK) >> BSH;        // 196 buckets of 512 nodes
    const int nchunk = (E + EPB - 1) / EPB;  // 391 chunks

    // workspace layout (u32 units); pairs 16B-aligned
    unsigned* bfill = (unsigned*)d_ws;                    // MAXNB*BPAD (16KB)
    unsigned* pairs = bfill + MAXNB * BPAD;               // nb*CAP (~19.3MB)
    int* esrc       = (int*)(pairs + (size_t)nb * CAP);   // nb*CAP (~19.3MB)
    unsigned* xd    = (unsigned*)(esrc + (size_t)nb * CAP); // 8*(N+1) (32B rows + dummy)
    float* dis      = (float*)(xd + (size_t)8 * (N + 1)); // N
    int* cnt        = (int*)(dis + N);                    // N
    int* rstart     = cnt + N;                            // N
    float* g2       = (float*)(rstart + N);               // 2*(N+1)
    // total ~ 44 MB

    const int B = 256;
    const int nz = MAXNB * BPAD;
    k_zero<<<(nz + B - 1) / B, B, 0, stream>>>(bfill, nz,
                                               xd + (size_t)8 * N,
                                               (unsigned*)(g2 + (size_t)2 * N));
    k_binA<<<nchunk, 512, 0, stream>>>(src, dst, bfill, pairs, E, nb);
    k_binB<<<nb, 1024, 0, stream>>>(pairs, bfill, x, cnt, dis, rstart, esrc, xd, N);
    k_layer1<<<(N * 8 + B - 1) / B, B, 0, stream>>>(xd, cnt, rstart, esrc, dis, b1, W1, W2, g2, N);
    k_out2<<<(N * 4 + B - 1) / B, B, 0, stream>>>(g2, cnt, rstart, esrc, dis, b2, out, N);
}